// Round 1
// baseline (13573.399 us; speedup 1.0000x reference)
//
#include <hip/hip_runtime.h>
#include <hip/hip_bf16.h>

#define D_ 128
#define DK_ 1280
#define H_ 64
#define K_ 10

// ---------------- scatter: edge segment-sums with f32 atomics ----------------
__global__ __launch_bounds__(256) void scatter_edges(
    const float* __restrict__ iemb_s, const float* __restrict__ uemb_s,
    const float* __restrict__ u_emb_sp,
    const int* __restrict__ eu, const int* __restrict__ ei,
    float* __restrict__ nu, float* __restrict__ ni, int E)
{
    long long gid = (long long)blockIdx.x * blockDim.x + threadIdx.x;
    int e = (int)(gid >> 5);
    int l = (int)(gid & 31);
    if (e >= E) return;
    int u  = eu[e];
    int it = ei[e];

    float4 iv = ((const float4*)(iemb_s + (size_t)it * D_))[l];
    float* nup = nu + (size_t)u * D_ + l * 4;
    atomicAdd(nup + 0, iv.x); atomicAdd(nup + 1, iv.y);
    atomicAdd(nup + 2, iv.z); atomicAdd(nup + 3, iv.w);

    float4 us = ((const float4*)(uemb_s  + (size_t)u * D_))[l];
    float4 up = ((const float4*)(u_emb_sp + (size_t)u * D_))[l];
    float* nip = ni + (size_t)it * D_ + l * 4;
    atomicAdd(nip + 0, 0.5f * (us.x + up.x));
    atomicAdd(nip + 1, 0.5f * (us.y + up.y));
    atomicAdd(nip + 2, 0.5f * (us.z + up.z));
    atomicAdd(nip + 3, 0.5f * (us.w + up.w));
}

// ---------------- tmp_embu = [uemb_s|uemb_t|u_emb_sp|nu] @ Wu + bu ----------------
__global__ __launch_bounds__(128) void gemm_u(
    const float* __restrict__ us, const float* __restrict__ ut,
    const float* __restrict__ usp, const float* __restrict__ nu,
    const float* __restrict__ Wu, const float* __restrict__ bu,
    float* __restrict__ out, int M)
{
    __shared__ float xs[8][512];
    int t = threadIdx.x;
    int row0 = blockIdx.x * 8;
    for (int r = 0; r < 8; ++r) {
        int row = row0 + r;
        if (row < M) {
            xs[r][t]       = us [(size_t)row * D_ + t];
            xs[r][128 + t] = ut [(size_t)row * D_ + t];
            xs[r][256 + t] = usp[(size_t)row * D_ + t];
            xs[r][384 + t] = nu [(size_t)row * D_ + t];
        }
    }
    __syncthreads();
    float acc[8];
    float bv = bu[t];
#pragma unroll
    for (int r = 0; r < 8; ++r) acc[r] = bv;
    for (int k = 0; k < 512; k += 4) {
        float w0 = Wu[(size_t)(k + 0) * D_ + t];
        float w1 = Wu[(size_t)(k + 1) * D_ + t];
        float w2 = Wu[(size_t)(k + 2) * D_ + t];
        float w3 = Wu[(size_t)(k + 3) * D_ + t];
#pragma unroll
        for (int r = 0; r < 8; ++r) {
            float4 x4 = *(const float4*)&xs[r][k];
            acc[r] = fmaf(x4.x, w0, acc[r]);
            acc[r] = fmaf(x4.y, w1, acc[r]);
            acc[r] = fmaf(x4.z, w2, acc[r]);
            acc[r] = fmaf(x4.w, w3, acc[r]);
        }
    }
    for (int r = 0; r < 8; ++r) {
        int row = row0 + r;
        if (row < M) out[(size_t)row * D_ + t] = acc[r];
    }
}

// ---------------- tmp_embi = [iemb_s|ni] @ Wi + bi ----------------
__global__ __launch_bounds__(128) void gemm_i(
    const float* __restrict__ is_, const float* __restrict__ ni,
    const float* __restrict__ Wi, const float* __restrict__ bi,
    float* __restrict__ out, int M)
{
    __shared__ float xs[8][256];
    int t = threadIdx.x;
    int row0 = blockIdx.x * 8;
    for (int r = 0; r < 8; ++r) {
        int row = row0 + r;
        if (row < M) {
            xs[r][t]       = is_[(size_t)row * D_ + t];
            xs[r][128 + t] = ni [(size_t)row * D_ + t];
        }
    }
    __syncthreads();
    float acc[8];
    float bv = bi[t];
#pragma unroll
    for (int r = 0; r < 8; ++r) acc[r] = bv;
    for (int k = 0; k < 256; k += 4) {
        float w0 = Wi[(size_t)(k + 0) * D_ + t];
        float w1 = Wi[(size_t)(k + 1) * D_ + t];
        float w2 = Wi[(size_t)(k + 2) * D_ + t];
        float w3 = Wi[(size_t)(k + 3) * D_ + t];
#pragma unroll
        for (int r = 0; r < 8; ++r) {
            float4 x4 = *(const float4*)&xs[r][k];
            acc[r] = fmaf(x4.x, w0, acc[r]);
            acc[r] = fmaf(x4.y, w1, acc[r]);
            acc[r] = fmaf(x4.z, w2, acc[r]);
            acc[r] = fmaf(x4.w, w3, acc[r]);
        }
    }
    for (int r = 0; r < 8; ++r) {
        int row = row0 + r;
        if (row < M) out[(size_t)row * D_ + t] = acc[r];
    }
}

// ---------------- fused MLP: y = norm( tanh(tanh(x@w1+b1)@w2+b2)@w3+b3 ) ----------------
__global__ __launch_bounds__(256) void mlp_kernel(
    const float* __restrict__ X,
    const float* __restrict__ w1, const float* __restrict__ b1,
    const float* __restrict__ w2, const float* __restrict__ b2,
    const float* __restrict__ w3, const float* __restrict__ b3,
    float* __restrict__ Y, int M)
{
    __shared__ float xs[8][D_];
    __shared__ float h1s[8][DK_];
    __shared__ float h2s[8][H_];
    __shared__ float nrm[8];
    __shared__ float wred[8][4];

    int t = threadIdx.x;      // 256
    int row0 = blockIdx.x * 8;

    for (int i = t; i < 8 * D_; i += 256) {
        int r = i >> 7, c = i & 127;
        int row = row0 + r;
        xs[r][c] = (row < M) ? X[(size_t)row * D_ + c] : 0.f;
    }
    __syncthreads();

    // phase 1: h1 = tanh(x @ w1 + b1)   [8][1280]
#pragma unroll 1
    for (int tile = 0; tile < 5; ++tile) {
        int c = tile * 256 + t;
        float acc[8];
        float bv = b1[c];
#pragma unroll
        for (int r = 0; r < 8; ++r) acc[r] = bv;
        for (int k = 0; k < D_; k += 4) {
            float w0 = w1[(size_t)(k + 0) * DK_ + c];
            float wv1 = w1[(size_t)(k + 1) * DK_ + c];
            float wv2 = w1[(size_t)(k + 2) * DK_ + c];
            float wv3 = w1[(size_t)(k + 3) * DK_ + c];
#pragma unroll
            for (int r = 0; r < 8; ++r) {
                float4 x4 = *(const float4*)&xs[r][k];
                acc[r] = fmaf(x4.x, w0, acc[r]);
                acc[r] = fmaf(x4.y, wv1, acc[r]);
                acc[r] = fmaf(x4.z, wv2, acc[r]);
                acc[r] = fmaf(x4.w, wv3, acc[r]);
            }
        }
#pragma unroll
        for (int r = 0; r < 8; ++r) h1s[r][c] = tanhf(acc[r]);
    }
    __syncthreads();

    // phase 2: h2 = tanh(h1 @ w2 + b2)  [8][64]
    {
        int c = t & 63;
        int r0 = t >> 6;   // rows r0 and r0+4
        float a0 = b2[c], a1 = b2[c];
        for (int k = 0; k < DK_; k += 4) {
            float w0 = w2[(size_t)(k + 0) * H_ + c];
            float wv1 = w2[(size_t)(k + 1) * H_ + c];
            float wv2 = w2[(size_t)(k + 2) * H_ + c];
            float wv3 = w2[(size_t)(k + 3) * H_ + c];
            float4 ha = *(const float4*)&h1s[r0][k];
            float4 hb = *(const float4*)&h1s[r0 + 4][k];
            a0 = fmaf(ha.x, w0, a0); a0 = fmaf(ha.y, wv1, a0);
            a0 = fmaf(ha.z, wv2, a0); a0 = fmaf(ha.w, wv3, a0);
            a1 = fmaf(hb.x, w0, a1); a1 = fmaf(hb.y, wv1, a1);
            a1 = fmaf(hb.z, wv2, a1); a1 = fmaf(hb.w, wv3, a1);
        }
        h2s[r0][c]     = tanhf(a0);
        h2s[r0 + 4][c] = tanhf(a1);
    }
    __syncthreads();

    // phase 3: y = h2 @ w3 + b3, keep in regs, reduce sum of squares
    float yv[5][8];
    float ssq[8];
#pragma unroll
    for (int r = 0; r < 8; ++r) ssq[r] = 0.f;
#pragma unroll 1
    for (int tile = 0; tile < 5; ++tile) {
        int c = tile * 256 + t;
        float acc[8];
        float bv = b3[c];
#pragma unroll
        for (int r = 0; r < 8; ++r) acc[r] = bv;
        for (int k = 0; k < H_; k += 4) {
            float w0 = w3[(size_t)(k + 0) * DK_ + c];
            float wv1 = w3[(size_t)(k + 1) * DK_ + c];
            float wv2 = w3[(size_t)(k + 2) * DK_ + c];
            float wv3 = w3[(size_t)(k + 3) * DK_ + c];
#pragma unroll
            for (int r = 0; r < 8; ++r) {
                float4 h4 = *(const float4*)&h2s[r][k];
                acc[r] = fmaf(h4.x, w0, acc[r]);
                acc[r] = fmaf(h4.y, wv1, acc[r]);
                acc[r] = fmaf(h4.z, wv2, acc[r]);
                acc[r] = fmaf(h4.w, wv3, acc[r]);
            }
        }
#pragma unroll
        for (int r = 0; r < 8; ++r) {
            yv[tile][r] = acc[r];
            ssq[r] = fmaf(acc[r], acc[r], ssq[r]);
        }
    }
    int lane = t & 63, w = t >> 6;
#pragma unroll
    for (int r = 0; r < 8; ++r) {
        float v = ssq[r];
        for (int off = 32; off; off >>= 1) v += __shfl_xor(v, off);
        if (lane == 0) wred[r][w] = v;
    }
    __syncthreads();
    if (t < 8) {
        float s = wred[t][0] + wred[t][1] + wred[t][2] + wred[t][3];
        nrm[t] = 1.f / fmaxf(sqrtf(s), 1e-12f);
    }
    __syncthreads();
#pragma unroll 1
    for (int tile = 0; tile < 5; ++tile) {
        int c = tile * 256 + t;
#pragma unroll
        for (int r = 0; r < 8; ++r) {
            int row = row0 + r;
            if (row < M) Y[(size_t)row * DK_ + c] = yv[tile][r] * nrm[r];
        }
    }
}

// ---------------- column sums of [M][1280] into sum[1280] ----------------
__global__ __launch_bounds__(256) void colsum_kernel(
    const float* __restrict__ A, float* __restrict__ sum, int M)
{
    int c = blockIdx.x * 256 + threadIdx.x;   // gridDim.x == 5 -> c < 1280
    int r0 = blockIdx.y * 512;
    int r1 = min(M, r0 + 512);
    float s = 0.f;
    for (int r = r0; r < r1; ++r) s += A[(size_t)r * DK_ + c];
    atomicAdd(&sum[c], s);
}

// ---------------- softmax over D axis for metau [U][128][10], in place ----------------
__global__ __launch_bounds__(64) void softmax_u_kernel(
    float* __restrict__ A, const float* __restrict__ bsum, float invM)
{
    __shared__ float rowb[DK_];
    int u = blockIdx.x;
    int t = threadIdx.x;   // 64
    size_t base = (size_t)u * DK_;
    for (int i = t; i < DK_; i += 64) rowb[i] = A[base + i] + bsum[i] * invM;
    __syncthreads();
#pragma unroll 1
    for (int k = 0; k < K_; ++k) {
        float v0 = rowb[t * K_ + k];
        float v1 = rowb[(t + 64) * K_ + k];
        float m = fmaxf(v0, v1);
        for (int off = 32; off; off >>= 1) m = fmaxf(m, __shfl_xor(m, off));
        float e0 = expf(v0 - m), e1 = expf(v1 - m);
        float s = e0 + e1;
        for (int off = 32; off; off >>= 1) s += __shfl_xor(s, off);
        float rs = 1.f / s;
        rowb[t * K_ + k] = e0 * rs;
        rowb[(t + 64) * K_ + k] = e1 * rs;
    }
    __syncthreads();
    for (int i = t; i < DK_; i += 64) A[base + i] = rowb[i];
}

// ---------------- softmax over K axis for metai [I][10][128], in place ----------------
__global__ __launch_bounds__(128) void softmax_i_kernel(
    float* __restrict__ A, const float* __restrict__ bsum, float invM)
{
    int it = blockIdx.x;
    int t = threadIdx.x;   // 128, d = t
    size_t base = (size_t)it * DK_;
    float v[K_];
    float m = -1e30f;
#pragma unroll
    for (int k = 0; k < K_; ++k) {
        v[k] = A[base + k * D_ + t] + bsum[k * D_ + t] * invM;
        m = fmaxf(m, v[k]);
    }
    float s = 0.f;
#pragma unroll
    for (int k = 0; k < K_; ++k) { v[k] = expf(v[k] - m); s += v[k]; }
    float rs = 1.f / s;
#pragma unroll
    for (int k = 0; k < K_; ++k) A[base + k * D_ + t] = v[k] * rs;
}

extern "C" void kernel_launch(void* const* d_in, const int* in_sizes, int n_in,
                              void* d_out, int out_size, void* d_ws, size_t ws_size,
                              hipStream_t stream)
{
    const float* uemb_s   = (const float*)d_in[0];
    const float* iemb_s   = (const float*)d_in[1];
    const float* uemb_t   = (const float*)d_in[2];
    const float* u_emb_sp = (const float*)d_in[3];
    const int*   eu       = (const int*)d_in[4];
    const int*   ei       = (const int*)d_in[5];
    const float* Wu  = (const float*)d_in[6];
    const float* bu  = (const float*)d_in[7];
    const float* Wi  = (const float*)d_in[8];
    const float* bi  = (const float*)d_in[9];
    const float* m1w1 = (const float*)d_in[10];
    const float* m1b1 = (const float*)d_in[11];
    const float* m1w2 = (const float*)d_in[12];
    const float* m1b2 = (const float*)d_in[13];
    const float* m1w3 = (const float*)d_in[14];
    const float* m1b3 = (const float*)d_in[15];
    const float* m2w1 = (const float*)d_in[16];
    const float* m2b1 = (const float*)d_in[17];
    const float* m2w2 = (const float*)d_in[18];
    const float* m2b2 = (const float*)d_in[19];
    const float* m2w3 = (const float*)d_in[20];
    const float* m2b3 = (const float*)d_in[21];

    const int U = in_sizes[0] / D_;
    const int I = in_sizes[1] / D_;
    const int E = in_sizes[4];

    float* ws   = (float*)d_ws;
    float* nu   = ws;
    float* ni   = nu + (size_t)U * D_;
    float* tmpu = ni + (size_t)I * D_;
    float* tmpi = tmpu + (size_t)U * D_;
    float* bsu  = tmpi + (size_t)I * D_;
    float* bsi  = bsu + DK_;

    float* outu = (float*)d_out;
    float* outi = outu + (size_t)U * DK_;

    // zero accumulators (nu and ni are contiguous)
    hipMemsetAsync(nu, 0, (size_t)(U + I) * D_ * sizeof(float), stream);
    hipMemsetAsync(bsu, 0, 2 * DK_ * sizeof(float), stream);

    // scatter
    long long tot = (long long)E * 32;
    int sblocks = (int)((tot + 255) / 256);
    scatter_edges<<<sblocks, 256, 0, stream>>>(iemb_s, uemb_s, u_emb_sp, eu, ei, nu, ni, E);

    // tmp embeddings
    gemm_u<<<(U + 7) / 8, 128, 0, stream>>>(uemb_s, uemb_t, u_emb_sp, nu, Wu, bu, tmpu, U);
    gemm_i<<<(I + 7) / 8, 128, 0, stream>>>(iemb_s, ni, Wi, bi, tmpi, I);

    // MLPs -> metau / metai directly into d_out
    mlp_kernel<<<(U + 7) / 8, 256, 0, stream>>>(tmpu, m1w1, m1b1, m1w2, m1b2, m1w3, m1b3, outu, U);
    mlp_kernel<<<(I + 7) / 8, 256, 0, stream>>>(tmpi, m2w1, m2b1, m2w2, m2b2, m2w3, m2b3, outi, I);

    // bias column sums
    dim3 cg_u(5, (U + 511) / 512);
    dim3 cg_i(5, (I + 511) / 512);
    colsum_kernel<<<cg_u, 256, 0, stream>>>(outu, bsu, U);
    colsum_kernel<<<cg_i, 256, 0, stream>>>(outi, bsi, I);

    // in-place softmax with mean bias
    softmax_u_kernel<<<U, 64, 0, stream>>>(outu, bsu, 1.0f / (float)U);
    softmax_i_kernel<<<I, 128, 0, stream>>>(outi, bsi, 1.0f / (float)I);
}

// Round 2
// 7953.471 us; speedup vs baseline: 1.7066x; 1.7066x over previous
//
#include <hip/hip_runtime.h>
#include <hip/hip_bf16.h>

#define D_ 128
#define DK_ 1280
#define H_ 64
#define K_ 10

// ---------------- CSR build: histogram ----------------
__global__ __launch_bounds__(256) void hist_kernel(
    const int* __restrict__ eu, const int* __restrict__ ei,
    int* __restrict__ cnt_u, int* __restrict__ cnt_i, int E)
{
    int e = blockIdx.x * 256 + threadIdx.x;
    if (e >= E) return;
    atomicAdd(&cnt_u[eu[e]], 1);
    atomicAdd(&cnt_i[ei[e]], 1);
}

// ---------------- CSR build: single-block exclusive scan ----------------
__global__ __launch_bounds__(1024) void scan_kernel(
    const int* __restrict__ cnt, int* __restrict__ off, int* __restrict__ cur, int n)
{
    __shared__ int wsum[16];
    __shared__ int carry_s;
    int t = threadIdx.x, lane = t & 63, w = t >> 6;
    if (t == 0) carry_s = 0;
    __syncthreads();
    for (int base = 0; base < n; base += 1024) {
        int i = base + t;
        int v = (i < n) ? cnt[i] : 0;
        int s = v;
        for (int o = 1; o < 64; o <<= 1) {
            int pv = __shfl_up(s, o);
            if (lane >= o) s += pv;
        }
        if (lane == 63) wsum[w] = s;
        __syncthreads();
        if (w == 0) {
            int ws_ = (lane < 16) ? wsum[lane] : 0;
            for (int o = 1; o < 16; o <<= 1) {
                int pv = __shfl_up(ws_, o);
                if (lane >= o) ws_ += pv;
            }
            if (lane < 16) wsum[lane] = ws_;
        }
        __syncthreads();
        int waveoff = (w == 0) ? 0 : wsum[w - 1];
        int carry = carry_s;
        int excl = carry + waveoff + (s - v);
        if (i < n) { off[i] = excl; cur[i] = excl; }
        __syncthreads();
        if (t == 0) carry_s = carry + wsum[15];
        __syncthreads();
    }
}

// ---------------- CSR build: fill adjacency ----------------
__global__ __launch_bounds__(256) void fill_kernel(
    const int* __restrict__ eu, const int* __restrict__ ei,
    int* __restrict__ cur_u, int* __restrict__ cur_i,
    int* __restrict__ adj_u, int* __restrict__ adj_i, int E)
{
    int e = blockIdx.x * 256 + threadIdx.x;
    if (e >= E) return;
    int u = eu[e], it = ei[e];
    adj_u[atomicAdd(&cur_u[u], 1)] = it;   // store item index
    adj_i[atomicAdd(&cur_i[it], 1)] = u;   // store user index
}

// ---------------- gather: nu[u] = sum_{items} iemb_s[item] ----------------
__global__ __launch_bounds__(256) void gather_u_kernel(
    const float* __restrict__ iemb,
    const int* __restrict__ off, const int* __restrict__ end_,
    const int* __restrict__ adj, float* __restrict__ nu, int U)
{
    int wid = (blockIdx.x * 256 + threadIdx.x) >> 6;
    if (wid >= U) return;
    int lane = threadIdx.x & 63;
    int beg = off[wid], end = end_[wid];
    float ax = 0.f, ay = 0.f;
    int j = beg;
    for (; j + 1 < end; j += 2) {
        int i0 = adj[j], i1 = adj[j + 1];
        float2 v0 = *(const float2*)(iemb + (size_t)i0 * D_ + lane * 2);
        float2 v1 = *(const float2*)(iemb + (size_t)i1 * D_ + lane * 2);
        ax += v0.x + v1.x; ay += v0.y + v1.y;
    }
    if (j < end) {
        int i0 = adj[j];
        float2 v0 = *(const float2*)(iemb + (size_t)i0 * D_ + lane * 2);
        ax += v0.x; ay += v0.y;
    }
    float2 o; o.x = ax; o.y = ay;
    *(float2*)(nu + (size_t)wid * D_ + lane * 2) = o;
}

// ---------------- gather: ni[i] = sum_{users} 0.5*(uemb_s[u]+u_emb_sp[u]) ----------------
__global__ __launch_bounds__(256) void gather_i_kernel(
    const float* __restrict__ ua, const float* __restrict__ ub,
    const int* __restrict__ off, const int* __restrict__ end_,
    const int* __restrict__ adj, float* __restrict__ ni, int I)
{
    int wid = (blockIdx.x * 256 + threadIdx.x) >> 6;
    if (wid >= I) return;
    int lane = threadIdx.x & 63;
    int beg = off[wid], end = end_[wid];
    float ax = 0.f, ay = 0.f;
    int j = beg;
    for (; j + 1 < end; j += 2) {
        int u0 = adj[j], u1 = adj[j + 1];
        float2 a0 = *(const float2*)(ua + (size_t)u0 * D_ + lane * 2);
        float2 b0 = *(const float2*)(ub + (size_t)u0 * D_ + lane * 2);
        float2 a1 = *(const float2*)(ua + (size_t)u1 * D_ + lane * 2);
        float2 b1 = *(const float2*)(ub + (size_t)u1 * D_ + lane * 2);
        ax += 0.5f * (a0.x + b0.x) + 0.5f * (a1.x + b1.x);
        ay += 0.5f * (a0.y + b0.y) + 0.5f * (a1.y + b1.y);
    }
    if (j < end) {
        int u0 = adj[j];
        float2 a0 = *(const float2*)(ua + (size_t)u0 * D_ + lane * 2);
        float2 b0 = *(const float2*)(ub + (size_t)u0 * D_ + lane * 2);
        ax += 0.5f * (a0.x + b0.x);
        ay += 0.5f * (a0.y + b0.y);
    }
    float2 o; o.x = ax; o.y = ay;
    *(float2*)(ni + (size_t)wid * D_ + lane * 2) = o;
}

// ---------------- uniform-x GEMM segment helper ----------------
__device__ __forceinline__ void gemm_seg(const float* __restrict__ S,
    const float* __restrict__ W, int t, float acc[8])
{
    for (int k = 0; k < D_; k += 4) {
        float w0 = W[(size_t)(k + 0) * D_ + t];
        float w1 = W[(size_t)(k + 1) * D_ + t];
        float w2 = W[(size_t)(k + 2) * D_ + t];
        float w3 = W[(size_t)(k + 3) * D_ + t];
#pragma unroll
        for (int r = 0; r < 8; ++r) {
            float4 x4 = *(const float4*)(S + r * D_ + k);   // block-uniform -> s_load
            acc[r] = fmaf(x4.x, w0, acc[r]);
            acc[r] = fmaf(x4.y, w1, acc[r]);
            acc[r] = fmaf(x4.z, w2, acc[r]);
            acc[r] = fmaf(x4.w, w3, acc[r]);
        }
    }
}

// ---------------- tmp_embu = [uemb_s|uemb_t|u_emb_sp|nu] @ Wu + bu ----------------
__global__ __launch_bounds__(128) void gemm_u(
    const float* __restrict__ us, const float* __restrict__ ut,
    const float* __restrict__ usp, const float* __restrict__ nu,
    const float* __restrict__ Wu, const float* __restrict__ bu,
    float* __restrict__ out, int M)
{
    int t = threadIdx.x;
    int row0 = blockIdx.x * 8;       // M % 8 == 0
    float acc[8];
    float bv = bu[t];
#pragma unroll
    for (int r = 0; r < 8; ++r) acc[r] = bv;
    gemm_seg(us  + (size_t)row0 * D_, Wu,                t, acc);
    gemm_seg(ut  + (size_t)row0 * D_, Wu + 1 * D_ * D_,  t, acc);
    gemm_seg(usp + (size_t)row0 * D_, Wu + 2 * D_ * D_,  t, acc);
    gemm_seg(nu  + (size_t)row0 * D_, Wu + 3 * D_ * D_,  t, acc);
#pragma unroll
    for (int r = 0; r < 8; ++r) out[(size_t)(row0 + r) * D_ + t] = acc[r];
}

// ---------------- tmp_embi = [iemb_s|ni] @ Wi + bi ----------------
__global__ __launch_bounds__(128) void gemm_i(
    const float* __restrict__ is_, const float* __restrict__ ni,
    const float* __restrict__ Wi, const float* __restrict__ bi,
    float* __restrict__ out, int M)
{
    int t = threadIdx.x;
    int row0 = blockIdx.x * 8;
    float acc[8];
    float bv = bi[t];
#pragma unroll
    for (int r = 0; r < 8; ++r) acc[r] = bv;
    gemm_seg(is_ + (size_t)row0 * D_, Wi,           t, acc);
    gemm_seg(ni  + (size_t)row0 * D_, Wi + D_ * D_, t, acc);
#pragma unroll
    for (int r = 0; r < 8; ++r) out[(size_t)(row0 + r) * D_ + t] = acc[r];
}

// ---------------- fused MLP ----------------
__global__ __launch_bounds__(256) void mlp_kernel(
    const float* __restrict__ X,
    const float* __restrict__ w1, const float* __restrict__ b1,
    const float* __restrict__ w2, const float* __restrict__ b2,
    const float* __restrict__ w3, const float* __restrict__ b3,
    float* __restrict__ Y, int M)
{
    __shared__ float h1s[8][DK_];
    __shared__ float h2s[8][H_];
    __shared__ float nrm[8];
    __shared__ float wred[8][4];

    int t = threadIdx.x;      // 256
    int row0 = blockIdx.x * 8;     // M % 8 == 0
    const float* __restrict__ Xb = X + (size_t)row0 * D_;

    // phase 1: h1 = tanh(x @ w1 + b1)   [8][1280]; x read uniform from global
#pragma unroll 1
    for (int tile = 0; tile < 5; ++tile) {
        int c = tile * 256 + t;
        float acc[8];
        float bv = b1[c];
#pragma unroll
        for (int r = 0; r < 8; ++r) acc[r] = bv;
        for (int k = 0; k < D_; k += 4) {
            float w0 = w1[(size_t)(k + 0) * DK_ + c];
            float wv1 = w1[(size_t)(k + 1) * DK_ + c];
            float wv2 = w1[(size_t)(k + 2) * DK_ + c];
            float wv3 = w1[(size_t)(k + 3) * DK_ + c];
#pragma unroll
            for (int r = 0; r < 8; ++r) {
                float4 x4 = *(const float4*)(Xb + r * D_ + k);   // uniform -> s_load
                acc[r] = fmaf(x4.x, w0, acc[r]);
                acc[r] = fmaf(x4.y, wv1, acc[r]);
                acc[r] = fmaf(x4.z, wv2, acc[r]);
                acc[r] = fmaf(x4.w, wv3, acc[r]);
            }
        }
#pragma unroll
        for (int r = 0; r < 8; ++r) h1s[r][c] = tanhf(acc[r]);
    }
    __syncthreads();

    // phase 2: h2 = tanh(h1 @ w2 + b2)  [8][64]
    {
        int c = t & 63;
        int r0 = t >> 6;   // rows r0 and r0+4
        float a0 = b2[c], a1 = b2[c];
        for (int k = 0; k < DK_; k += 4) {
            float w0 = w2[(size_t)(k + 0) * H_ + c];
            float wv1 = w2[(size_t)(k + 1) * H_ + c];
            float wv2 = w2[(size_t)(k + 2) * H_ + c];
            float wv3 = w2[(size_t)(k + 3) * H_ + c];
            float4 ha = *(const float4*)&h1s[r0][k];
            float4 hb = *(const float4*)&h1s[r0 + 4][k];
            a0 = fmaf(ha.x, w0, a0); a0 = fmaf(ha.y, wv1, a0);
            a0 = fmaf(ha.z, wv2, a0); a0 = fmaf(ha.w, wv3, a0);
            a1 = fmaf(hb.x, w0, a1); a1 = fmaf(hb.y, wv1, a1);
            a1 = fmaf(hb.z, wv2, a1); a1 = fmaf(hb.w, wv3, a1);
        }
        h2s[r0][c]     = tanhf(a0);
        h2s[r0 + 4][c] = tanhf(a1);
    }
    __syncthreads();

    // phase 3: y = h2 @ w3 + b3, keep in regs, reduce sum of squares
    float yv[5][8];
    float ssq[8];
#pragma unroll
    for (int r = 0; r < 8; ++r) ssq[r] = 0.f;
#pragma unroll 1
    for (int tile = 0; tile < 5; ++tile) {
        int c = tile * 256 + t;
        float acc[8];
        float bv = b3[c];
#pragma unroll
        for (int r = 0; r < 8; ++r) acc[r] = bv;
        for (int k = 0; k < H_; k += 4) {
            float w0 = w3[(size_t)(k + 0) * DK_ + c];
            float wv1 = w3[(size_t)(k + 1) * DK_ + c];
            float wv2 = w3[(size_t)(k + 2) * DK_ + c];
            float wv3 = w3[(size_t)(k + 3) * DK_ + c];
#pragma unroll
            for (int r = 0; r < 8; ++r) {
                float4 h4 = *(const float4*)&h2s[r][k];
                acc[r] = fmaf(h4.x, w0, acc[r]);
                acc[r] = fmaf(h4.y, wv1, acc[r]);
                acc[r] = fmaf(h4.z, wv2, acc[r]);
                acc[r] = fmaf(h4.w, wv3, acc[r]);
            }
        }
#pragma unroll
        for (int r = 0; r < 8; ++r) {
            yv[tile][r] = acc[r];
            ssq[r] = fmaf(acc[r], acc[r], ssq[r]);
        }
    }
    int lane = t & 63, w = t >> 6;
#pragma unroll
    for (int r = 0; r < 8; ++r) {
        float v = ssq[r];
        for (int off = 32; off; off >>= 1) v += __shfl_xor(v, off);
        if (lane == 0) wred[r][w] = v;
    }
    __syncthreads();
    if (t < 8) {
        float s = wred[t][0] + wred[t][1] + wred[t][2] + wred[t][3];
        nrm[t] = 1.f / fmaxf(sqrtf(s), 1e-12f);
    }
    __syncthreads();
#pragma unroll 1
    for (int tile = 0; tile < 5; ++tile) {
        int c = tile * 256 + t;
#pragma unroll
        for (int r = 0; r < 8; ++r)
            Y[(size_t)(row0 + r) * DK_ + c] = yv[tile][r] * nrm[r];
    }
}

// ---------------- column sums of [M][1280] into sum[1280] ----------------
__global__ __launch_bounds__(256) void colsum_kernel(
    const float* __restrict__ A, float* __restrict__ sum, int M)
{
    int c = blockIdx.x * 256 + threadIdx.x;   // gridDim.x == 5 -> c < 1280
    int r0 = blockIdx.y * 512;
    int r1 = min(M, r0 + 512);
    float s = 0.f;
    for (int r = r0; r < r1; ++r) s += A[(size_t)r * DK_ + c];
    atomicAdd(&sum[c], s);
}

// ---------------- softmax over D axis for metau [U][128][10], in place ----------------
__global__ __launch_bounds__(64) void softmax_u_kernel(
    float* __restrict__ A, const float* __restrict__ bsum, float invM)
{
    __shared__ float rowb[DK_];
    int u = blockIdx.x;
    int t = threadIdx.x;   // 64
    size_t base = (size_t)u * DK_;
    for (int i = t; i < DK_; i += 64) rowb[i] = A[base + i] + bsum[i] * invM;
    __syncthreads();
#pragma unroll 1
    for (int k = 0; k < K_; ++k) {
        float v0 = rowb[t * K_ + k];
        float v1 = rowb[(t + 64) * K_ + k];
        float m = fmaxf(v0, v1);
        for (int off = 32; off; off >>= 1) m = fmaxf(m, __shfl_xor(m, off));
        float e0 = expf(v0 - m), e1 = expf(v1 - m);
        float s = e0 + e1;
        for (int off = 32; off; off >>= 1) s += __shfl_xor(s, off);
        float rs = 1.f / s;
        rowb[t * K_ + k] = e0 * rs;
        rowb[(t + 64) * K_ + k] = e1 * rs;
    }
    __syncthreads();
    for (int i = t; i < DK_; i += 64) A[base + i] = rowb[i];
}

// ---------------- softmax over K axis for metai [I][10][128], in place ----------------
__global__ __launch_bounds__(128) void softmax_i_kernel(
    float* __restrict__ A, const float* __restrict__ bsum, float invM)
{
    int it = blockIdx.x;
    int t = threadIdx.x;   // 128
    size_t base = (size_t)it * DK_;
    float v[K_];
    float m = -1e30f;
#pragma unroll
    for (int k = 0; k < K_; ++k) {
        v[k] = A[base + k * D_ + t] + bsum[k * D_ + t] * invM;
        m = fmaxf(m, v[k]);
    }
    float s = 0.f;
#pragma unroll
    for (int k = 0; k < K_; ++k) { v[k] = expf(v[k] - m); s += v[k]; }
    float rs = 1.f / s;
#pragma unroll
    for (int k = 0; k < K_; ++k) A[base + k * D_ + t] = v[k] * rs;
}

extern "C" void kernel_launch(void* const* d_in, const int* in_sizes, int n_in,
                              void* d_out, int out_size, void* d_ws, size_t ws_size,
                              hipStream_t stream)
{
    const float* uemb_s   = (const float*)d_in[0];
    const float* iemb_s   = (const float*)d_in[1];
    const float* uemb_t   = (const float*)d_in[2];
    const float* u_emb_sp = (const float*)d_in[3];
    const int*   eu       = (const int*)d_in[4];
    const int*   ei       = (const int*)d_in[5];
    const float* Wu  = (const float*)d_in[6];
    const float* bu  = (const float*)d_in[7];
    const float* Wi  = (const float*)d_in[8];
    const float* bi  = (const float*)d_in[9];
    const float* m1w1 = (const float*)d_in[10];
    const float* m1b1 = (const float*)d_in[11];
    const float* m1w2 = (const float*)d_in[12];
    const float* m1b2 = (const float*)d_in[13];
    const float* m1w3 = (const float*)d_in[14];
    const float* m1b3 = (const float*)d_in[15];
    const float* m2w1 = (const float*)d_in[16];
    const float* m2b1 = (const float*)d_in[17];
    const float* m2w2 = (const float*)d_in[18];
    const float* m2b2 = (const float*)d_in[19];
    const float* m2w3 = (const float*)d_in[20];
    const float* m2b3 = (const float*)d_in[21];

    const int U = in_sizes[0] / D_;
    const int I = in_sizes[1] / D_;
    const int E = in_sizes[4];

    float* ws   = (float*)d_ws;
    float* nu   = ws;
    float* ni   = nu + (size_t)U * D_;
    float* tmpu = ni + (size_t)I * D_;
    float* tmpi = tmpu + (size_t)U * D_;
    float* bsu  = tmpi + (size_t)I * D_;
    float* bsi  = bsu + DK_;
    int* cnt_u  = (int*)(bsi + DK_);
    int* cnt_i  = cnt_u + U;
    int* off_u  = cnt_i + I;
    int* cur_u  = off_u + U;
    int* off_i  = cur_u + U;
    int* cur_i  = off_i + I;
    int* adj_u  = cur_i + I;
    int* adj_i  = adj_u + E;

    float* outu = (float*)d_out;
    float* outi = outu + (size_t)U * DK_;

    hipMemsetAsync(cnt_u, 0, (size_t)(U + I) * sizeof(int), stream);
    hipMemsetAsync(bsu, 0, 2 * DK_ * sizeof(float), stream);

    int eb = (E + 255) / 256;
    hist_kernel<<<eb, 256, 0, stream>>>(eu, ei, cnt_u, cnt_i, E);
    scan_kernel<<<1, 1024, 0, stream>>>(cnt_u, off_u, cur_u, U);
    scan_kernel<<<1, 1024, 0, stream>>>(cnt_i, off_i, cur_i, I);
    fill_kernel<<<eb, 256, 0, stream>>>(eu, ei, cur_u, cur_i, adj_u, adj_i, E);

    gather_u_kernel<<<(U + 3) / 4, 256, 0, stream>>>(iemb_s, off_u, cur_u, adj_u, nu, U);
    gather_i_kernel<<<(I + 3) / 4, 256, 0, stream>>>(uemb_s, u_emb_sp, off_i, cur_i, adj_i, ni, I);

    gemm_u<<<U / 8, 128, 0, stream>>>(uemb_s, uemb_t, u_emb_sp, nu, Wu, bu, tmpu, U);
    gemm_i<<<I / 8, 128, 0, stream>>>(iemb_s, ni, Wi, bi, tmpi, I);

    mlp_kernel<<<U / 8, 256, 0, stream>>>(tmpu, m1w1, m1b1, m1w2, m1b2, m1w3, m1b3, outu, U);
    mlp_kernel<<<I / 8, 256, 0, stream>>>(tmpi, m2w1, m2b1, m2w2, m2b2, m2w3, m2b3, outi, I);

    dim3 cg_u(5, (U + 511) / 512);
    dim3 cg_i(5, (I + 511) / 512);
    colsum_kernel<<<cg_u, 256, 0, stream>>>(outu, bsu, U);
    colsum_kernel<<<cg_i, 256, 0, stream>>>(outi, bsi, I);

    softmax_u_kernel<<<U, 64, 0, stream>>>(outu, bsu, 1.0f / (float)U);
    softmax_i_kernel<<<I, 128, 0, stream>>>(outi, bsi, 1.0f / (float)I);
}

// Round 3
// 1631.004 us; speedup vs baseline: 8.3221x; 4.8764x over previous
//
#include <hip/hip_runtime.h>
#include <hip/hip_bf16.h>

#define D_ 128
#define DK_ 1280
#define K_ 10

typedef __attribute__((ext_vector_type(8))) short bh8;   // 8 bf16 = 4 VGPR (MFMA A/B frag)
typedef __attribute__((ext_vector_type(4))) short bh4;
typedef __attribute__((ext_vector_type(4))) float f32x4; // MFMA C/D frag

__device__ __forceinline__ short f2b(float f) {
    unsigned u = __builtin_bit_cast(unsigned, f);
    u += 0x7fffu + ((u >> 16) & 1u);          // RNE
    return (short)(u >> 16);
}
__device__ __forceinline__ float b2f(short s) {
    unsigned u = ((unsigned)(unsigned short)s) << 16;
    return __builtin_bit_cast(float, u);
}
__device__ __forceinline__ float tanh_fast(float x) {
    float e = __expf(2.f * x);
    return 1.f - __fdividef(2.f, e + 1.f);    // exact at +-inf, no NaN
}
__device__ __forceinline__ f32x4 mfma16(bh8 a, bh8 b, f32x4 c) {
    return __builtin_amdgcn_mfma_f32_16x16x32_bf16(a, b, c, 0, 0, 0);
}

// ---------------- f32 -> bf16 bulk convert (n % 4 == 0) ----------------
__global__ __launch_bounds__(256) void cvt_bf16(
    const float* __restrict__ in, short* __restrict__ out, int n4)
{
    int i = blockIdx.x * 256 + threadIdx.x;
    if (i >= n4) return;
    float4 v = ((const float4*)in)[i];
    bh4 s;
    s[0] = f2b(v.x); s[1] = f2b(v.y); s[2] = f2b(v.z); s[3] = f2b(v.w);
    ((bh4*)out)[i] = s;
}

// ---------------- pack W[K][N] f32 -> bf16 MFMA-fragment order ----------------
// out[((tile*KK + kk)*64 + lane)*8 + j] = W[kk*32 + (lane>>4)*8 + j][tile*16 + (lane&15)]
__global__ __launch_bounds__(256) void pack_w(
    const float* __restrict__ W, short* __restrict__ out, int K, int N)
{
    int o = blockIdx.x * 256 + threadIdx.x;
    if (o >= K * N) return;
    int j    = o & 7;
    int lane = (o >> 3) & 63;
    int rest = o >> 9;
    int KK = K >> 5;
    int kk = rest % KK;
    int tile = rest / KK;
    int k = kk * 32 + (lane >> 4) * 8 + j;
    int n = tile * 16 + (lane & 15);
    out[o] = f2b(W[(size_t)k * N + n]);
}

// ---------------- CSR build ----------------
__global__ __launch_bounds__(256) void hist_kernel(
    const int* __restrict__ eu, const int* __restrict__ ei,
    int* __restrict__ cnt_u, int* __restrict__ cnt_i, int E)
{
    int e = blockIdx.x * 256 + threadIdx.x;
    if (e >= E) return;
    atomicAdd(&cnt_u[eu[e]], 1);
    atomicAdd(&cnt_i[ei[e]], 1);
}

__global__ __launch_bounds__(1024) void scan_kernel(
    const int* __restrict__ cnt, int* __restrict__ off, int* __restrict__ cur, int n)
{
    __shared__ int wsum[16];
    __shared__ int carry_s;
    int t = threadIdx.x, lane = t & 63, w = t >> 6;
    if (t == 0) carry_s = 0;
    __syncthreads();
    for (int base = 0; base < n; base += 1024) {
        int i = base + t;
        int v = (i < n) ? cnt[i] : 0;
        int s = v;
        for (int o = 1; o < 64; o <<= 1) {
            int pv = __shfl_up(s, o);
            if (lane >= o) s += pv;
        }
        if (lane == 63) wsum[w] = s;
        __syncthreads();
        if (w == 0) {
            int ws_ = (lane < 16) ? wsum[lane] : 0;
            for (int o = 1; o < 16; o <<= 1) {
                int pv = __shfl_up(ws_, o);
                if (lane >= o) ws_ += pv;
            }
            if (lane < 16) wsum[lane] = ws_;
        }
        __syncthreads();
        int waveoff = (w == 0) ? 0 : wsum[w - 1];
        int carry = carry_s;
        int excl = carry + waveoff + (s - v);
        if (i < n) { off[i] = excl; cur[i] = excl; }
        __syncthreads();
        if (t == 0) carry_s = carry + wsum[15];
        __syncthreads();
    }
}

__global__ __launch_bounds__(256) void fill_kernel(
    const int* __restrict__ eu, const int* __restrict__ ei,
    int* __restrict__ cur_u, int* __restrict__ cur_i,
    int* __restrict__ adj_u, int* __restrict__ adj_i, int E)
{
    int e = blockIdx.x * 256 + threadIdx.x;
    if (e >= E) return;
    int u = eu[e], it = ei[e];
    adj_u[atomicAdd(&cur_u[u], 1)] = it;
    adj_i[atomicAdd(&cur_i[it], 1)] = u;
}

// ---------------- gathers (bf16 in, bf16 out) ----------------
__global__ __launch_bounds__(256) void gather_u_kernel(
    const short* __restrict__ iemb,
    const int* __restrict__ off, const int* __restrict__ end_,
    const int* __restrict__ adj, short* __restrict__ nu, int U)
{
    int wid = (blockIdx.x * 256 + threadIdx.x) >> 6;
    if (wid >= U) return;
    int lane = threadIdx.x & 63;
    int beg = off[wid], end = end_[wid];
    float ax = 0.f, ay = 0.f;
    int j = beg;
    for (; j + 1 < end; j += 2) {
        unsigned a = *(const unsigned*)(iemb + (size_t)adj[j]     * D_ + lane * 2);
        unsigned b = *(const unsigned*)(iemb + (size_t)adj[j + 1] * D_ + lane * 2);
        ax += b2f((short)(a & 0xffff)) + b2f((short)(b & 0xffff));
        ay += b2f((short)(a >> 16))    + b2f((short)(b >> 16));
    }
    if (j < end) {
        unsigned a = *(const unsigned*)(iemb + (size_t)adj[j] * D_ + lane * 2);
        ax += b2f((short)(a & 0xffff));
        ay += b2f((short)(a >> 16));
    }
    unsigned o = ((unsigned)(unsigned short)f2b(ay) << 16) | (unsigned short)(unsigned)f2b(ax);
    *(unsigned*)(nu + (size_t)wid * D_ + lane * 2) = o;
}

__global__ __launch_bounds__(256) void gather_i_kernel(
    const short* __restrict__ ua, const short* __restrict__ ub,
    const int* __restrict__ off, const int* __restrict__ end_,
    const int* __restrict__ adj, short* __restrict__ ni, int I)
{
    int wid = (blockIdx.x * 256 + threadIdx.x) >> 6;
    if (wid >= I) return;
    int lane = threadIdx.x & 63;
    int beg = off[wid], end = end_[wid];
    float ax = 0.f, ay = 0.f;
    for (int j = beg; j < end; ++j) {
        size_t ro = (size_t)adj[j] * D_ + lane * 2;
        unsigned a = *(const unsigned*)(ua + ro);
        unsigned b = *(const unsigned*)(ub + ro);
        ax += 0.5f * (b2f((short)(a & 0xffff)) + b2f((short)(b & 0xffff)));
        ay += 0.5f * (b2f((short)(a >> 16))    + b2f((short)(b >> 16)));
    }
    unsigned o = ((unsigned)(unsigned short)f2b(ay) << 16) | (unsigned short)(unsigned)f2b(ax);
    *(unsigned*)(ni + (size_t)wid * D_ + lane * 2) = o;
}

// ---------------- fused gemm + MLP + norm + bias-colsum ----------------
// 16 rows/block, 4 waves. LDS pool layout (byte offsets):
//   x2  [16][128] bf16 swz : 0    .. 4096
//   xcat[16][KCAT]bf16 swz : 4096 .. 4096+KCAT*32   (overlays h1; dead before h1 written)
//   h1  [16][1280]bf16 swz : 4096 .. 45056
//   h2  [16][64]  bf16 swz : 45056.. 47104
//   ybuf[80 tiles][520B]   : 0    .. 41600          (overlays x2+h1; both dead in phase3)
template<int KCAT, int NARR>
__global__ __launch_bounds__(256, 3) void fused_mlp(
    const short* __restrict__ A0, const short* __restrict__ A1,
    const short* __restrict__ A2, const short* __restrict__ A3,
    const short* __restrict__ Wg, const float* __restrict__ bg,
    const short* __restrict__ W1p, const float* __restrict__ b1,
    const short* __restrict__ W2p, const float* __restrict__ b2,
    const short* __restrict__ W3p, const float* __restrict__ b3,
    float* __restrict__ Y, float* __restrict__ bsum)
{
    __shared__ char pool[47104];
    __shared__ float wred[4][16];
    __shared__ float nrms[16];

    short* x2 = (short*)pool;
    short* xc = (short*)(pool + 4096);
    short* h1 = (short*)(pool + 4096);
    short* h2 = (short*)(pool + 45056);
    short* yb = (short*)pool;

    const int t = threadIdx.x;
    const int l = t & 63;
    const int w = t >> 6;
    const int lr = l & 15;        // A row / C col within tile
    const int lg = l >> 4;        // k-chunk / C row-group
    const size_t rb0 = (size_t)blockIdx.x * 16;

    // ---- stage concat-x into LDS (swizzled 16B slots) ----
    constexpr int CH_ROW = KCAT / 8;          // 16B chunks per row
    constexpr int NITER = (16 * CH_ROW) / 256;
#pragma unroll
    for (int j = 0; j < NITER; ++j) {
        int idx = j * 256 + t;
        int row = idx / CH_ROW;
        int slot = idx % CH_ROW;
        int a = slot >> 4, cs = slot & 15;
        const short* src = (NARR == 4) ? (a == 0 ? A0 : a == 1 ? A1 : a == 2 ? A2 : A3)
                                       : (a == 0 ? A0 : A1);
        bh8 v = *(const bh8*)(src + (rb0 + row) * D_ + cs * 8);
        int sl2 = slot ^ (row & 7);
        *(bh8*)(xc + row * KCAT + sl2 * 8) = v;
    }
    __syncthreads();

    // ---- gemm: tmp = xcat @ Wg + bg -> x2 (bf16) ----
    {
        constexpr int KK_G = KCAT / 32;
        f32x4 accA0 = {0,0,0,0}, accB0 = accA0, accA1 = accA0, accB1 = accA0;
#pragma unroll 4
        for (int kk = 0; kk < KK_G; ++kk) {
            int slot = kk * 4 + lg;
            bh8 af = *(const bh8*)(xc + lr * KCAT + (slot ^ (lr & 7)) * 8);
            bh8 b0 = *(const bh8*)(Wg + (((size_t)(2 * w)     * KK_G + kk) * 64 + l) * 8);
            bh8 b1v = *(const bh8*)(Wg + (((size_t)(2 * w + 1) * KK_G + kk) * 64 + l) * 8);
            if (kk & 1) { accB0 = mfma16(af, b0, accB0); accB1 = mfma16(af, b1v, accB1); }
            else        { accA0 = mfma16(af, b0, accA0); accA1 = mfma16(af, b1v, accA1); }
        }
#pragma unroll
        for (int r = 0; r < 4; ++r) {
            int row = lg * 4 + r;
            int c0 = (2 * w) * 16 + lr;
            int c1 = c0 + 16;
            x2[row * 128 + (((c0 >> 3) ^ (row & 7)) * 8) + (l & 7)] = f2b(accA0[r] + accB0[r] + bg[c0]);
            x2[row * 128 + (((c1 >> 3) ^ (row & 7)) * 8) + (l & 7)] = f2b(accA1[r] + accB1[r] + bg[c1]);
        }
    }
    __syncthreads();

    // ---- phase 1: h1 = tanh(x2 @ W1 + b1) ----
    {
        bh8 a1f[4];
#pragma unroll
        for (int kk = 0; kk < 4; ++kk) {
            int slot = kk * 4 + lg;
            a1f[kk] = *(const bh8*)(x2 + lr * 128 + (slot ^ (lr & 7)) * 8);
        }
#pragma unroll 2
        for (int tile = w * 20; tile < w * 20 + 20; ++tile) {
            float bv = b1[tile * 16 + lr];
            f32x4 acc = {bv, bv, bv, bv};
#pragma unroll
            for (int kk = 0; kk < 4; ++kk) {
                bh8 bf_ = *(const bh8*)(W1p + (((size_t)tile * 4 + kk) * 64 + l) * 8);
                acc = mfma16(a1f[kk], bf_, acc);
            }
#pragma unroll
            for (int r = 0; r < 4; ++r) {
                int row = lg * 4 + r;
                int col = tile * 16 + lr;
                h1[row * 1280 + (((col >> 3) ^ (row & 7)) * 8) + (l & 7)] = f2b(tanh_fast(acc[r]));
            }
        }
    }
    __syncthreads();

    // ---- phase 2: h2 = tanh(h1 @ W2 + b2), wave w owns n-tile w ----
    {
        float bv = b2[w * 16 + lr];
        f32x4 accA = {bv, bv, bv, bv}, accB = {0,0,0,0};
#pragma unroll 4
        for (int kk = 0; kk < 40; ++kk) {
            int slot = kk * 4 + lg;
            bh8 af = *(const bh8*)(h1 + lr * 1280 + (slot ^ (lr & 7)) * 8);
            bh8 bf_ = *(const bh8*)(W2p + (((size_t)w * 40 + kk) * 64 + l) * 8);
            if (kk & 1) accB = mfma16(af, bf_, accB);
            else        accA = mfma16(af, bf_, accA);
        }
#pragma unroll
        for (int r = 0; r < 4; ++r) {
            int row = lg * 4 + r;
            int col = w * 16 + lr;
            h2[row * 64 + (((col >> 3) ^ (row & 7)) * 8) + (l & 7)] = f2b(tanh_fast(accA[r] + accB[r]));
        }
    }
    __syncthreads();

    // ---- phase 3: y = h2 @ W3 + b3 -> ybuf(bf16), ssq ----
    {
        bh8 a3[2];
#pragma unroll
        for (int kk = 0; kk < 2; ++kk) {
            int slot = kk * 4 + lg;
            a3[kk] = *(const bh8*)(h2 + lr * 64 + (slot ^ (lr & 7)) * 8);
        }
        float ssq[4] = {0.f, 0.f, 0.f, 0.f};
#pragma unroll 2
        for (int tile = w * 20; tile < w * 20 + 20; ++tile) {
            float bv = b3[tile * 16 + lr];
            f32x4 acc = {bv, bv, bv, bv};
            bh8 b0 = *(const bh8*)(W3p + (((size_t)tile * 2 + 0) * 64 + l) * 8);
            bh8 b1v = *(const bh8*)(W3p + (((size_t)tile * 2 + 1) * 64 + l) * 8);
            acc = mfma16(a3[0], b0, acc);
            acc = mfma16(a3[1], b1v, acc);
            bh4 pk;
#pragma unroll
            for (int r = 0; r < 4; ++r) {
                ssq[r] = fmaf(acc[r], acc[r], ssq[r]);
                pk[r] = f2b(acc[r]);
            }
            *(bh4*)(yb + tile * 260 + l * 4) = pk;   // 520B stride, lane-linear
        }
#pragma unroll
        for (int off = 1; off < 16; off <<= 1) {
#pragma unroll
            for (int r = 0; r < 4; ++r) ssq[r] += __shfl_xor(ssq[r], off);
        }
        if (lr == 0) {
#pragma unroll
            for (int r = 0; r < 4; ++r) wred[w][lg * 4 + r] = ssq[r];
        }
    }
    __syncthreads();
    if (t < 16) {
        float s = wred[0][t] + wred[1][t] + wred[2][t] + wred[3][t];
        nrms[t] = 1.f / fmaxf(sqrtf(s), 1e-12f);
    }
    __syncthreads();

    // ---- writeout: normalized f32, coalesced; fused bias colsum ----
    {
        float csum[5] = {0.f, 0.f, 0.f, 0.f, 0.f};
        for (int row = 0; row < 16; ++row) {
            float nv = nrms[row];
            int lph = (row >> 2) << 4;
            int r = row & 3;
#pragma unroll
            for (int ch = 0; ch < 5; ++ch) {
                int c = ch * 256 + t;
                int tile = c >> 4;
                int lanep = lph | (c & 15);
                float v = b2f(yb[tile * 260 + lanep * 4 + r]) * nv;
                Y[(rb0 + row) * DK_ + c] = v;
                csum[ch] += v;
            }
        }
#pragma unroll
        for (int ch = 0; ch < 5; ++ch) atomicAdd(&bsum[ch * 256 + t], csum[ch]);
    }
}

// ---------------- softmax over D axis for metau [U][128][10], in place ----------------
__global__ __launch_bounds__(64) void softmax_u_kernel(
    float* __restrict__ A, const float* __restrict__ bsum, float invM)
{
    __shared__ float rowb[DK_];
    int u = blockIdx.x;
    int t = threadIdx.x;
    size_t base = (size_t)u * DK_;
    for (int i = t; i < DK_; i += 64) rowb[i] = A[base + i] + bsum[i] * invM;
    __syncthreads();
#pragma unroll 1
    for (int k = 0; k < K_; ++k) {
        float v0 = rowb[t * K_ + k];
        float v1 = rowb[(t + 64) * K_ + k];
        float m = fmaxf(v0, v1);
        for (int off = 32; off; off >>= 1) m = fmaxf(m, __shfl_xor(m, off));
        float e0 = expf(v0 - m), e1 = expf(v1 - m);
        float s = e0 + e1;
        for (int off = 32; off; off >>= 1) s += __shfl_xor(s, off);
        float rs = 1.f / s;
        rowb[t * K_ + k] = e0 * rs;
        rowb[(t + 64) * K_ + k] = e1 * rs;
    }
    __syncthreads();
    for (int i = t; i < DK_; i += 64) A[base + i] = rowb[i];
}

// ---------------- softmax over K axis for metai [I][10][128], in place ----------------
__global__ __launch_bounds__(128) void softmax_i_kernel(
    float* __restrict__ A, const float* __restrict__ bsum, float invM)
{
    int it = blockIdx.x;
    int t = threadIdx.x;
    size_t base = (size_t)it * DK_;
    float v[K_];
    float m = -1e30f;
#pragma unroll
    for (int k = 0; k < K_; ++k) {
        v[k] = A[base + k * D_ + t] + bsum[k * D_ + t] * invM;
        m = fmaxf(m, v[k]);
    }
    float s = 0.f;
#pragma unroll
    for (int k = 0; k < K_; ++k) { v[k] = expf(v[k] - m); s += v[k]; }
    float rs = 1.f / s;
#pragma unroll
    for (int k = 0; k < K_; ++k) A[base + k * D_ + t] = v[k] * rs;
}

extern "C" void kernel_launch(void* const* d_in, const int* in_sizes, int n_in,
                              void* d_out, int out_size, void* d_ws, size_t ws_size,
                              hipStream_t stream)
{
    const float* uemb_s   = (const float*)d_in[0];
    const float* iemb_s   = (const float*)d_in[1];
    const float* uemb_t   = (const float*)d_in[2];
    const float* u_emb_sp = (const float*)d_in[3];
    const int*   eu       = (const int*)d_in[4];
    const int*   ei       = (const int*)d_in[5];
    const float* Wu  = (const float*)d_in[6];
    const float* bu  = (const float*)d_in[7];
    const float* Wi  = (const float*)d_in[8];
    const float* bi  = (const float*)d_in[9];
    const float* m1w1 = (const float*)d_in[10];
    const float* m1b1 = (const float*)d_in[11];
    const float* m1w2 = (const float*)d_in[12];
    const float* m1b2 = (const float*)d_in[13];
    const float* m1w3 = (const float*)d_in[14];
    const float* m1b3 = (const float*)d_in[15];
    const float* m2w1 = (const float*)d_in[16];
    const float* m2b1 = (const float*)d_in[17];
    const float* m2w2 = (const float*)d_in[18];
    const float* m2b2 = (const float*)d_in[19];
    const float* m2w3 = (const float*)d_in[20];
    const float* m2b3 = (const float*)d_in[21];

    const int U = in_sizes[0] / D_;
    const int I = in_sizes[1] / D_;
    const int E = in_sizes[4];

    char* p = (char*)d_ws;
    auto alloc = [&](size_t bytes) { char* r = p; p += (bytes + 255) & ~(size_t)255; return r; };

    short* usb  = (short*)alloc((size_t)U * D_ * 2);
    short* utb  = (short*)alloc((size_t)U * D_ * 2);
    short* uspb = (short*)alloc((size_t)U * D_ * 2);
    short* isb  = (short*)alloc((size_t)I * D_ * 2);
    short* nub  = (short*)alloc((size_t)U * D_ * 2);
    short* nib  = (short*)alloc((size_t)I * D_ * 2);
    short* WgU  = (short*)alloc(512 * 128 * 2);
    short* WgI  = (short*)alloc(256 * 128 * 2);
    short* W1U  = (short*)alloc(128 * 1280 * 2);
    short* W2U  = (short*)alloc(1280 * 64 * 2);
    short* W3U  = (short*)alloc(64 * 1280 * 2);
    short* W1I  = (short*)alloc(128 * 1280 * 2);
    short* W2I  = (short*)alloc(1280 * 64 * 2);
    short* W3I  = (short*)alloc(64 * 1280 * 2);
    float* bsu  = (float*)alloc(DK_ * 4);
    float* bsi  = (float*)alloc(DK_ * 4);
    int* cnt_u  = (int*)alloc((size_t)(U + I) * 4);   // cnt_u, cnt_i contiguous
    int* cnt_i  = cnt_u + U;
    int* off_u  = (int*)alloc((size_t)U * 4);
    int* cur_u  = (int*)alloc((size_t)U * 4);
    int* off_i  = (int*)alloc((size_t)I * 4);
    int* cur_i  = (int*)alloc((size_t)I * 4);
    int* adj_u  = (int*)alloc((size_t)E * 4);
    int* adj_i  = (int*)alloc((size_t)E * 4);

    float* outu = (float*)d_out;
    float* outi = outu + (size_t)U * DK_;

    hipMemsetAsync(cnt_u, 0, (size_t)(U + I) * 4, stream);
    hipMemsetAsync(bsu, 0, DK_ * 4, stream);
    hipMemsetAsync(bsi, 0, DK_ * 4, stream);

    // bf16 conversions
    int n4u = U * D_ / 4, n4i = I * D_ / 4;
    cvt_bf16<<<(n4u + 255) / 256, 256, 0, stream>>>(uemb_s,   usb,  n4u);
    cvt_bf16<<<(n4u + 255) / 256, 256, 0, stream>>>(uemb_t,   utb,  n4u);
    cvt_bf16<<<(n4u + 255) / 256, 256, 0, stream>>>(u_emb_sp, uspb, n4u);
    cvt_bf16<<<(n4i + 255) / 256, 256, 0, stream>>>(iemb_s,   isb,  n4i);

    // weight packing
    auto packW = [&](const float* W, short* o, int K, int N) {
        pack_w<<<(K * N + 255) / 256, 256, 0, stream>>>(W, o, K, N);
    };
    packW(Wu,   WgU, 512, 128);
    packW(Wi,   WgI, 256, 128);
    packW(m1w1, W1U, 128, 1280);
    packW(m1w2, W2U, 1280, 64);
    packW(m1w3, W3U, 64, 1280);
    packW(m2w1, W1I, 128, 1280);
    packW(m2w2, W2I, 1280, 64);
    packW(m2w3, W3I, 64, 1280);

    // CSR + gathers
    int eb = (E + 255) / 256;
    hist_kernel<<<eb, 256, 0, stream>>>(eu, ei, cnt_u, cnt_i, E);
    scan_kernel<<<1, 1024, 0, stream>>>(cnt_u, off_u, cur_u, U);
    scan_kernel<<<1, 1024, 0, stream>>>(cnt_i, off_i, cur_i, I);
    fill_kernel<<<eb, 256, 0, stream>>>(eu, ei, cur_u, cur_i, adj_u, adj_i, E);
    gather_u_kernel<<<(U + 3) / 4, 256, 0, stream>>>(isb, off_u, cur_u, adj_u, nub, U);
    gather_i_kernel<<<(I + 3) / 4, 256, 0, stream>>>(usb, uspb, off_i, cur_i, adj_i, nib, I);

    // fused gemm + MLP + norm + colsum
    fused_mlp<512, 4><<<U / 16, 256, 0, stream>>>(
        usb, utb, uspb, nub, WgU, bu, W1U, m1b1, W2U, m1b2, W3U, m1b3, outu, bsu);
    fused_mlp<256, 2><<<I / 16, 256, 0, stream>>>(
        isb, nib, nullptr, nullptr, WgI, bi, W1I, m2b1, W2I, m2b2, W3I, m2b3, outi, bsi);

    // softmax with mean bias
    softmax_u_kernel<<<U, 64, 0, stream>>>(outu, bsu, 1.0f / (float)U);
    softmax_i_kernel<<<I, 128, 0, stream>>>(outi, bsi, 1.0f / (float)I);
}

// Round 4
// 1520.930 us; speedup vs baseline: 8.9244x; 1.0724x over previous
//
#include <hip/hip_runtime.h>
#include <hip/hip_bf16.h>

#define D_ 128
#define DK_ 1280
#define K_ 10

typedef __attribute__((ext_vector_type(8))) short bh8;   // 8 bf16 = 4 VGPR (MFMA A/B frag)
typedef __attribute__((ext_vector_type(4))) short bh4;
typedef __attribute__((ext_vector_type(4))) float f32x4; // MFMA C/D frag

__device__ __forceinline__ short f2b(float f) {
    unsigned u = __builtin_bit_cast(unsigned, f);
    u += 0x7fffu + ((u >> 16) & 1u);          // RNE
    return (short)(u >> 16);
}
__device__ __forceinline__ float b2f(short s) {
    unsigned u = ((unsigned)(unsigned short)s) << 16;
    return __builtin_bit_cast(float, u);
}
__device__ __forceinline__ float tanh_fast(float x) {
    float e = __expf(2.f * x);
    return 1.f - __fdividef(2.f, e + 1.f);    // exact at +-inf, no NaN
}
__device__ __forceinline__ f32x4 mfma16(bh8 a, bh8 b, f32x4 c) {
    return __builtin_amdgcn_mfma_f32_16x16x32_bf16(a, b, c, 0, 0, 0);
}

// ---------------- f32 -> bf16 bulk convert (n % 4 == 0) ----------------
__global__ __launch_bounds__(256) void cvt_bf16(
    const float* __restrict__ in, short* __restrict__ out, int n4)
{
    int i = blockIdx.x * 256 + threadIdx.x;
    if (i >= n4) return;
    float4 v = ((const float4*)in)[i];
    bh4 s;
    s[0] = f2b(v.x); s[1] = f2b(v.y); s[2] = f2b(v.z); s[3] = f2b(v.w);
    ((bh4*)out)[i] = s;
}

// ---------------- pack W[K][N] f32 -> bf16 MFMA-fragment order ----------------
// out[((tile*KK + kk)*64 + lane)*8 + j] = W[kk*32 + (lane>>4)*8 + j][tile*16 + (lane&15)]
__global__ __launch_bounds__(256) void pack_w(
    const float* __restrict__ W, short* __restrict__ out, int K, int N)
{
    int o = blockIdx.x * 256 + threadIdx.x;
    if (o >= K * N) return;
    int j    = o & 7;
    int lane = (o >> 3) & 63;
    int rest = o >> 9;
    int KK = K >> 5;
    int kk = rest % KK;
    int tile = rest / KK;
    int k = kk * 32 + (lane >> 4) * 8 + j;
    int n = tile * 16 + (lane & 15);
    out[o] = f2b(W[(size_t)k * N + n]);
}

// ---------------- CSR build ----------------
__global__ __launch_bounds__(256) void hist_kernel(
    const int* __restrict__ eu, const int* __restrict__ ei,
    int* __restrict__ cnt_u, int* __restrict__ cnt_i, int E)
{
    int e = blockIdx.x * 256 + threadIdx.x;
    if (e >= E) return;
    atomicAdd(&cnt_u[eu[e]], 1);
    atomicAdd(&cnt_i[ei[e]], 1);
}

__global__ __launch_bounds__(1024) void scan_kernel(
    const int* __restrict__ cnt, int* __restrict__ off, int* __restrict__ cur, int n)
{
    __shared__ int wsum[16];
    __shared__ int carry_s;
    int t = threadIdx.x, lane = t & 63, w = t >> 6;
    if (t == 0) carry_s = 0;
    __syncthreads();
    for (int base = 0; base < n; base += 1024) {
        int i = base + t;
        int v = (i < n) ? cnt[i] : 0;
        int s = v;
        for (int o = 1; o < 64; o <<= 1) {
            int pv = __shfl_up(s, o);
            if (lane >= o) s += pv;
        }
        if (lane == 63) wsum[w] = s;
        __syncthreads();
        if (w == 0) {
            int ws_ = (lane < 16) ? wsum[lane] : 0;
            for (int o = 1; o < 16; o <<= 1) {
                int pv = __shfl_up(ws_, o);
                if (lane >= o) ws_ += pv;
            }
            if (lane < 16) wsum[lane] = ws_;
        }
        __syncthreads();
        int waveoff = (w == 0) ? 0 : wsum[w - 1];
        int carry = carry_s;
        int excl = carry + waveoff + (s - v);
        if (i < n) { off[i] = excl; cur[i] = excl; }
        __syncthreads();
        if (t == 0) carry_s = carry + wsum[15];
        __syncthreads();
    }
}

__global__ __launch_bounds__(256) void fill_kernel(
    const int* __restrict__ eu, const int* __restrict__ ei,
    int* __restrict__ cur_u, int* __restrict__ cur_i,
    int* __restrict__ adj_u, int* __restrict__ adj_i, int E)
{
    int e = blockIdx.x * 256 + threadIdx.x;
    if (e >= E) return;
    int u = eu[e], it = ei[e];
    adj_u[atomicAdd(&cur_u[u], 1)] = it;
    adj_i[atomicAdd(&cur_i[it], 1)] = u;
}

// ---------------- gathers (bf16 in, bf16 out) ----------------
__global__ __launch_bounds__(256) void gather_u_kernel(
    const short* __restrict__ iemb,
    const int* __restrict__ off, const int* __restrict__ end_,
    const int* __restrict__ adj, short* __restrict__ nu, int U)
{
    int wid = (blockIdx.x * 256 + threadIdx.x) >> 6;
    if (wid >= U) return;
    int lane = threadIdx.x & 63;
    int beg = off[wid], end = end_[wid];
    float ax = 0.f, ay = 0.f;
    int j = beg;
    for (; j + 3 < end; j += 4) {
        unsigned a = *(const unsigned*)(iemb + (size_t)adj[j]     * D_ + lane * 2);
        unsigned b = *(const unsigned*)(iemb + (size_t)adj[j + 1] * D_ + lane * 2);
        unsigned c = *(const unsigned*)(iemb + (size_t)adj[j + 2] * D_ + lane * 2);
        unsigned d = *(const unsigned*)(iemb + (size_t)adj[j + 3] * D_ + lane * 2);
        ax += b2f((short)(a & 0xffff)) + b2f((short)(b & 0xffff))
            + b2f((short)(c & 0xffff)) + b2f((short)(d & 0xffff));
        ay += b2f((short)(a >> 16)) + b2f((short)(b >> 16))
            + b2f((short)(c >> 16)) + b2f((short)(d >> 16));
    }
    for (; j < end; ++j) {
        unsigned a = *(const unsigned*)(iemb + (size_t)adj[j] * D_ + lane * 2);
        ax += b2f((short)(a & 0xffff));
        ay += b2f((short)(a >> 16));
    }
    unsigned o = ((unsigned)(unsigned short)f2b(ay) << 16) | (unsigned short)(unsigned)f2b(ax);
    *(unsigned*)(nu + (size_t)wid * D_ + lane * 2) = o;
}

__global__ __launch_bounds__(256) void gather_i_kernel(
    const short* __restrict__ ua, const short* __restrict__ ub,
    const int* __restrict__ off, const int* __restrict__ end_,
    const int* __restrict__ adj, short* __restrict__ ni, int I)
{
    int wid = (blockIdx.x * 256 + threadIdx.x) >> 6;
    if (wid >= I) return;
    int lane = threadIdx.x & 63;
    int beg = off[wid], end = end_[wid];
    float ax = 0.f, ay = 0.f;
    int j = beg;
    for (; j + 1 < end; j += 2) {
        size_t r0 = (size_t)adj[j] * D_ + lane * 2;
        size_t r1 = (size_t)adj[j + 1] * D_ + lane * 2;
        unsigned a0 = *(const unsigned*)(ua + r0);
        unsigned b0 = *(const unsigned*)(ub + r0);
        unsigned a1 = *(const unsigned*)(ua + r1);
        unsigned b1 = *(const unsigned*)(ub + r1);
        ax += 0.5f * (b2f((short)(a0 & 0xffff)) + b2f((short)(b0 & 0xffff)))
            + 0.5f * (b2f((short)(a1 & 0xffff)) + b2f((short)(b1 & 0xffff)));
        ay += 0.5f * (b2f((short)(a0 >> 16)) + b2f((short)(b0 >> 16)))
            + 0.5f * (b2f((short)(a1 >> 16)) + b2f((short)(b1 >> 16)));
    }
    if (j < end) {
        size_t r0 = (size_t)adj[j] * D_ + lane * 2;
        unsigned a0 = *(const unsigned*)(ua + r0);
        unsigned b0 = *(const unsigned*)(ub + r0);
        ax += 0.5f * (b2f((short)(a0 & 0xffff)) + b2f((short)(b0 & 0xffff)));
        ay += 0.5f * (b2f((short)(a0 >> 16)) + b2f((short)(b0 >> 16)));
    }
    unsigned o = ((unsigned)(unsigned short)f2b(ay) << 16) | (unsigned short)(unsigned)f2b(ax);
    *(unsigned*)(ni + (size_t)wid * D_ + lane * 2) = o;
}

// ---------------- fused gemm + MLP + norm + bias-colsum; y out as bf16 ----------------
template<int KCAT, int NARR>
__global__ __launch_bounds__(256, 3) void fused_mlp(
    const short* __restrict__ A0, const short* __restrict__ A1,
    const short* __restrict__ A2, const short* __restrict__ A3,
    const short* __restrict__ Wg, const float* __restrict__ bg,
    const short* __restrict__ W1p, const float* __restrict__ b1,
    const short* __restrict__ W2p, const float* __restrict__ b2,
    const short* __restrict__ W3p, const float* __restrict__ b3,
    short* __restrict__ Ybf, float* __restrict__ bsum)
{
    __shared__ char pool[47104];
    __shared__ float wred[4][16];
    __shared__ float nrms[16];

    short* x2 = (short*)pool;
    short* xc = (short*)(pool + 4096);
    short* h1 = (short*)(pool + 4096);
    short* h2 = (short*)(pool + 45056);
    short* yb = (short*)pool;

    const int t = threadIdx.x;
    const int l = t & 63;
    const int w = t >> 6;
    const int lr = l & 15;
    const int lg = l >> 4;
    const size_t rb0 = (size_t)blockIdx.x * 16;

    // ---- stage concat-x into LDS (swizzled 16B slots) ----
    constexpr int CH_ROW = KCAT / 8;
    constexpr int NITER = (16 * CH_ROW) / 256;
#pragma unroll
    for (int j = 0; j < NITER; ++j) {
        int idx = j * 256 + t;
        int row = idx / CH_ROW;
        int slot = idx % CH_ROW;
        int a = slot >> 4, cs = slot & 15;
        const short* src = (NARR == 4) ? (a == 0 ? A0 : a == 1 ? A1 : a == 2 ? A2 : A3)
                                       : (a == 0 ? A0 : A1);
        bh8 v = *(const bh8*)(src + (rb0 + row) * D_ + cs * 8);
        int sl2 = slot ^ (row & 7);
        *(bh8*)(xc + row * KCAT + sl2 * 8) = v;
    }
    __syncthreads();

    // ---- gemm: tmp = xcat @ Wg + bg -> x2 (bf16) ----
    {
        constexpr int KK_G = KCAT / 32;
        f32x4 accA0 = {0,0,0,0}, accB0 = accA0, accA1 = accA0, accB1 = accA0;
#pragma unroll 4
        for (int kk = 0; kk < KK_G; ++kk) {
            int slot = kk * 4 + lg;
            bh8 af = *(const bh8*)(xc + lr * KCAT + (slot ^ (lr & 7)) * 8);
            bh8 b0 = *(const bh8*)(Wg + (((size_t)(2 * w)     * KK_G + kk) * 64 + l) * 8);
            bh8 b1v = *(const bh8*)(Wg + (((size_t)(2 * w + 1) * KK_G + kk) * 64 + l) * 8);
            if (kk & 1) { accB0 = mfma16(af, b0, accB0); accB1 = mfma16(af, b1v, accB1); }
            else        { accA0 = mfma16(af, b0, accA0); accA1 = mfma16(af, b1v, accA1); }
        }
#pragma unroll
        for (int r = 0; r < 4; ++r) {
            int row = lg * 4 + r;
            int c0 = (2 * w) * 16 + lr;
            int c1 = c0 + 16;
            x2[row * 128 + (((c0 >> 3) ^ (row & 7)) * 8) + (l & 7)] = f2b(accA0[r] + accB0[r] + bg[c0]);
            x2[row * 128 + (((c1 >> 3) ^ (row & 7)) * 8) + (l & 7)] = f2b(accA1[r] + accB1[r] + bg[c1]);
        }
    }
    __syncthreads();

    // ---- phase 1: h1 = tanh(x2 @ W1 + b1) ----
    {
        bh8 a1f[4];
#pragma unroll
        for (int kk = 0; kk < 4; ++kk) {
            int slot = kk * 4 + lg;
            a1f[kk] = *(const bh8*)(x2 + lr * 128 + (slot ^ (lr & 7)) * 8);
        }
#pragma unroll 2
        for (int tile = w * 20; tile < w * 20 + 20; ++tile) {
            float bv = b1[tile * 16 + lr];
            f32x4 acc = {bv, bv, bv, bv};
#pragma unroll
            for (int kk = 0; kk < 4; ++kk) {
                bh8 bf_ = *(const bh8*)(W1p + (((size_t)tile * 4 + kk) * 64 + l) * 8);
                acc = mfma16(a1f[kk], bf_, acc);
            }
#pragma unroll
            for (int r = 0; r < 4; ++r) {
                int row = lg * 4 + r;
                int col = tile * 16 + lr;
                h1[row * 1280 + (((col >> 3) ^ (row & 7)) * 8) + (l & 7)] = f2b(tanh_fast(acc[r]));
            }
        }
    }
    __syncthreads();

    // ---- phase 2: h2 = tanh(h1 @ W2 + b2), wave w owns n-tile w ----
    {
        float bv = b2[w * 16 + lr];
        f32x4 accA = {bv, bv, bv, bv}, accB = {0,0,0,0};
#pragma unroll 4
        for (int kk = 0; kk < 40; ++kk) {
            int slot = kk * 4 + lg;
            bh8 af = *(const bh8*)(h1 + lr * 1280 + (slot ^ (lr & 7)) * 8);
            bh8 bf_ = *(const bh8*)(W2p + (((size_t)w * 40 + kk) * 64 + l) * 8);
            if (kk & 1) accB = mfma16(af, bf_, accB);
            else        accA = mfma16(af, bf_, accA);
        }
#pragma unroll
        for (int r = 0; r < 4; ++r) {
            int row = lg * 4 + r;
            int col = w * 16 + lr;
            h2[row * 64 + (((col >> 3) ^ (row & 7)) * 8) + (l & 7)] = f2b(tanh_fast(accA[r] + accB[r]));
        }
    }
    __syncthreads();

    // ---- phase 3: y = h2 @ W3 + b3 -> ybuf(bf16), ssq ----
    {
        bh8 a3[2];
#pragma unroll
        for (int kk = 0; kk < 2; ++kk) {
            int slot = kk * 4 + lg;
            a3[kk] = *(const bh8*)(h2 + lr * 64 + (slot ^ (lr & 7)) * 8);
        }
        float ssq[4] = {0.f, 0.f, 0.f, 0.f};
#pragma unroll 2
        for (int tile = w * 20; tile < w * 20 + 20; ++tile) {
            float bv = b3[tile * 16 + lr];
            f32x4 acc = {bv, bv, bv, bv};
            bh8 b0 = *(const bh8*)(W3p + (((size_t)tile * 2 + 0) * 64 + l) * 8);
            bh8 b1v = *(const bh8*)(W3p + (((size_t)tile * 2 + 1) * 64 + l) * 8);
            acc = mfma16(a3[0], b0, acc);
            acc = mfma16(a3[1], b1v, acc);
            bh4 pk;
#pragma unroll
            for (int r = 0; r < 4; ++r) {
                ssq[r] = fmaf(acc[r], acc[r], ssq[r]);
                pk[r] = f2b(acc[r]);
            }
            *(bh4*)(yb + tile * 260 + l * 4) = pk;
        }
#pragma unroll
        for (int off = 1; off < 16; off <<= 1) {
#pragma unroll
            for (int r = 0; r < 4; ++r) ssq[r] += __shfl_xor(ssq[r], off);
        }
        if (lr == 0) {
#pragma unroll
            for (int r = 0; r < 4; ++r) wred[w][lg * 4 + r] = ssq[r];
        }
    }
    __syncthreads();
    if (t < 16) {
        float s = wred[0][t] + wred[1][t] + wred[2][t] + wred[3][t];
        nrms[t] = 1.f / fmaxf(sqrtf(s), 1e-12f);
    }
    __syncthreads();

    // ---- writeout: normalized bf16, coalesced; fused bias colsum (f32) ----
    {
        float csum[5] = {0.f, 0.f, 0.f, 0.f, 0.f};
        for (int row = 0; row < 16; ++row) {
            float nv = nrms[row];
            int lph = (row >> 2) << 4;
            int r = row & 3;
#pragma unroll
            for (int ch = 0; ch < 5; ++ch) {
                int c = ch * 256 + t;
                int tile = c >> 4;
                int lanep = lph | (c & 15);
                float v = b2f(yb[tile * 260 + lanep * 4 + r]) * nv;
                Ybf[(rb0 + row) * DK_ + c] = f2b(v);
                csum[ch] += v;
            }
        }
#pragma unroll
        for (int ch = 0; ch < 5; ++ch) atomicAdd(&bsum[ch * 256 + t], csum[ch]);
    }
}

// ---------------- softmax over D axis: metau [U][128][10], bf16 in -> f32 out ----------------
__global__ __launch_bounds__(64) void softmax_u_kernel(
    const short* __restrict__ Ab, const float* __restrict__ bsum, float invM,
    float* __restrict__ Out)
{
    __shared__ float rowb[DK_];
    int u = blockIdx.x;
    int t = threadIdx.x;
    size_t base = (size_t)u * DK_;
    for (int i = t; i < DK_ / 2; i += 64) {
        unsigned a = ((const unsigned*)(Ab + base))[i];
        float2 bv = ((const float2*)bsum)[i];
        rowb[2 * i]     = b2f((short)(a & 0xffff)) + bv.x * invM;
        rowb[2 * i + 1] = b2f((short)(a >> 16))    + bv.y * invM;
    }
    __syncthreads();
#pragma unroll 1
    for (int k = 0; k < K_; ++k) {
        float v0 = rowb[t * K_ + k];
        float v1 = rowb[(t + 64) * K_ + k];
        float m = fmaxf(v0, v1);
        for (int off = 32; off; off >>= 1) m = fmaxf(m, __shfl_xor(m, off));
        float e0 = expf(v0 - m), e1 = expf(v1 - m);
        float s = e0 + e1;
        for (int off = 32; off; off >>= 1) s += __shfl_xor(s, off);
        float rs = 1.f / s;
        rowb[t * K_ + k] = e0 * rs;
        rowb[(t + 64) * K_ + k] = e1 * rs;
    }
    __syncthreads();
    for (int i = t; i < DK_; i += 64) Out[base + i] = rowb[i];
}

// ---------------- softmax over K axis: metai [I][10][128], bf16 in -> f32 out ----------------
__global__ __launch_bounds__(128) void softmax_i_kernel(
    const short* __restrict__ Ab, const float* __restrict__ bsum, float invM,
    float* __restrict__ Out)
{
    int it = blockIdx.x;
    int t = threadIdx.x;
    size_t base = (size_t)it * DK_;
    float v[K_];
    float m = -1e30f;
#pragma unroll
    for (int k = 0; k < K_; ++k) {
        v[k] = b2f(Ab[base + k * D_ + t]) + bsum[k * D_ + t] * invM;
        m = fmaxf(m, v[k]);
    }
    float s = 0.f;
#pragma unroll
    for (int k = 0; k < K_; ++k) { v[k] = expf(v[k] - m); s += v[k]; }
    float rs = 1.f / s;
#pragma unroll
    for (int k = 0; k < K_; ++k) Out[base + k * D_ + t] = v[k] * rs;
}

extern "C" void kernel_launch(void* const* d_in, const int* in_sizes, int n_in,
                              void* d_out, int out_size, void* d_ws, size_t ws_size,
                              hipStream_t stream)
{
    const float* uemb_s   = (const float*)d_in[0];
    const float* iemb_s   = (const float*)d_in[1];
    const float* uemb_t   = (const float*)d_in[2];
    const float* u_emb_sp = (const float*)d_in[3];
    const int*   eu       = (const int*)d_in[4];
    const int*   ei       = (const int*)d_in[5];
    const float* Wu  = (const float*)d_in[6];
    const float* bu  = (const float*)d_in[7];
    const float* Wi  = (const float*)d_in[8];
    const float* bi  = (const float*)d_in[9];
    const float* m1w1 = (const float*)d_in[10];
    const float* m1b1 = (const float*)d_in[11];
    const float* m1w2 = (const float*)d_in[12];
    const float* m1b2 = (const float*)d_in[13];
    const float* m1w3 = (const float*)d_in[14];
    const float* m1b3 = (const float*)d_in[15];
    const float* m2w1 = (const float*)d_in[16];
    const float* m2b1 = (const float*)d_in[17];
    const float* m2w2 = (const float*)d_in[18];
    const float* m2b2 = (const float*)d_in[19];
    const float* m2w3 = (const float*)d_in[20];
    const float* m2b3 = (const float*)d_in[21];

    const int U = in_sizes[0] / D_;
    const int I = in_sizes[1] / D_;
    const int E = in_sizes[4];

    char* p = (char*)d_ws;
    auto alloc = [&](size_t bytes) { char* r = p; p += (bytes + 255) & ~(size_t)255; return r; };

    short* usb  = (short*)alloc((size_t)U * D_ * 2);
    short* utb  = (short*)alloc((size_t)U * D_ * 2);
    short* uspb = (short*)alloc((size_t)U * D_ * 2);
    short* isb  = (short*)alloc((size_t)I * D_ * 2);
    short* nub  = (short*)alloc((size_t)U * D_ * 2);
    short* nib  = (short*)alloc((size_t)I * D_ * 2);
    short* ybu  = (short*)alloc((size_t)U * DK_ * 2);
    short* ybi  = (short*)alloc((size_t)I * DK_ * 2);
    short* WgU  = (short*)alloc(512 * 128 * 2);
    short* WgI  = (short*)alloc(256 * 128 * 2);
    short* W1U  = (short*)alloc(128 * 1280 * 2);
    short* W2U  = (short*)alloc(1280 * 64 * 2);
    short* W3U  = (short*)alloc(64 * 1280 * 2);
    short* W1I  = (short*)alloc(128 * 1280 * 2);
    short* W2I  = (short*)alloc(1280 * 64 * 2);
    short* W3I  = (short*)alloc(64 * 1280 * 2);
    float* bsu  = (float*)alloc(DK_ * 4);
    float* bsi  = (float*)alloc(DK_ * 4);
    int* cnt_u  = (int*)alloc((size_t)(U + I) * 4);
    int* cnt_i  = cnt_u + U;
    int* off_u  = (int*)alloc((size_t)U * 4);
    int* cur_u  = (int*)alloc((size_t)U * 4);
    int* off_i  = (int*)alloc((size_t)I * 4);
    int* cur_i  = (int*)alloc((size_t)I * 4);
    int* adj_u  = (int*)alloc((size_t)E * 4);
    int* adj_i  = (int*)alloc((size_t)E * 4);

    float* outu = (float*)d_out;
    float* outi = outu + (size_t)U * DK_;

    hipMemsetAsync(cnt_u, 0, (size_t)(U + I) * 4, stream);
    hipMemsetAsync(bsu, 0, DK_ * 4, stream);
    hipMemsetAsync(bsi, 0, DK_ * 4, stream);

    // bf16 conversions
    int n4u = U * D_ / 4, n4i = I * D_ / 4;
    cvt_bf16<<<(n4u + 255) / 256, 256, 0, stream>>>(uemb_s,   usb,  n4u);
    cvt_bf16<<<(n4u + 255) / 256, 256, 0, stream>>>(uemb_t,   utb,  n4u);
    cvt_bf16<<<(n4u + 255) / 256, 256, 0, stream>>>(u_emb_sp, uspb, n4u);
    cvt_bf16<<<(n4i + 255) / 256, 256, 0, stream>>>(iemb_s,   isb,  n4i);

    // weight packing
    auto packW = [&](const float* W, short* o, int K, int N) {
        pack_w<<<(K * N + 255) / 256, 256, 0, stream>>>(W, o, K, N);
    };
    packW(Wu,   WgU, 512, 128);
    packW(Wi,   WgI, 256, 128);
    packW(m1w1, W1U, 128, 1280);
    packW(m1w2, W2U, 1280, 64);
    packW(m1w3, W3U, 64, 1280);
    packW(m2w1, W1I, 128, 1280);
    packW(m2w2, W2I, 1280, 64);
    packW(m2w3, W3I, 64, 1280);

    // CSR + gathers
    int eb = (E + 255) / 256;
    hist_kernel<<<eb, 256, 0, stream>>>(eu, ei, cnt_u, cnt_i, E);
    scan_kernel<<<1, 1024, 0, stream>>>(cnt_u, off_u, cur_u, U);
    scan_kernel<<<1, 1024, 0, stream>>>(cnt_i, off_i, cur_i, I);
    fill_kernel<<<eb, 256, 0, stream>>>(eu, ei, cur_u, cur_i, adj_u, adj_i, E);
    gather_u_kernel<<<(U + 3) / 4, 256, 0, stream>>>(isb, off_u, cur_u, adj_u, nub, U);
    gather_i_kernel<<<(I + 3) / 4, 256, 0, stream>>>(usb, uspb, off_i, cur_i, adj_i, nib, I);

    // fused gemm + MLP + norm + colsum -> bf16 y in ws
    fused_mlp<512, 4><<<U / 16, 256, 0, stream>>>(
        usb, utb, uspb, nub, WgU, bu, W1U, m1b1, W2U, m1b2, W3U, m1b3, ybu, bsu);
    fused_mlp<256, 2><<<I / 16, 256, 0, stream>>>(
        isb, nib, nullptr, nullptr, WgI, bi, W1I, m2b1, W2I, m2b2, W3I, m2b3, ybi, bsi);

    // softmax with mean bias: bf16 in, f32 out
    softmax_u_kernel<<<U, 64, 0, stream>>>(ybu, bsu, 1.0f / (float)U, outu);
    softmax_i_kernel<<<I, 128, 0, stream>>>(ybi, bsi, 1.0f / (float)I, outi);
}

// Round 5
// 1010.728 us; speedup vs baseline: 13.4293x; 1.5048x over previous
//
#include <hip/hip_runtime.h>
#include <hip/hip_bf16.h>

#define D_ 128
#define DK_ 1280
#define K_ 10

typedef __attribute__((ext_vector_type(8))) short bh8;   // 8 bf16 = 4 VGPR (MFMA A/B frag)
typedef __attribute__((ext_vector_type(4))) short bh4;
typedef __attribute__((ext_vector_type(4))) float f32x4; // MFMA C/D frag

__device__ __forceinline__ short f2b(float f) {
    unsigned u = __builtin_bit_cast(unsigned, f);
    u += 0x7fffu + ((u >> 16) & 1u);          // RNE
    return (short)(u >> 16);
}
__device__ __forceinline__ float b2f(short s) {
    unsigned u = ((unsigned)(unsigned short)s) << 16;
    return __builtin_bit_cast(float, u);
}
__device__ __forceinline__ float tanh_fast(float x) {
    float e = __expf(2.f * x);
    return 1.f - __fdividef(2.f, e + 1.f);    // exact at +-inf, no NaN
}
__device__ __forceinline__ f32x4 mfma16(bh8 a, bh8 b, f32x4 c) {
    return __builtin_amdgcn_mfma_f32_16x16x32_bf16(a, b, c, 0, 0, 0);
}

// block-exclusive scan of one int per thread (256 threads)
__device__ __forceinline__ int blk_excl_scan(int v, int t) {
    __shared__ int wp[4];
    int lane = t & 63, w = t >> 6;
    int s = v;
    for (int o = 1; o < 64; o <<= 1) {
        int pv = __shfl_up(s, o);
        if (lane >= o) s += pv;
    }
    if (lane == 63) wp[w] = s;
    __syncthreads();
    if (t == 0) {
        int a = 0;
#pragma unroll
        for (int k = 0; k < 4; ++k) { int x = wp[k]; wp[k] = a; a += x; }
    }
    __syncthreads();
    int r = s - v + wp[w];
    __syncthreads();
    return r;
}

// ---------------- f32 -> bf16 bulk convert (n % 4 == 0) ----------------
__global__ __launch_bounds__(256) void cvt_bf16(
    const float* __restrict__ in, short* __restrict__ out, int n4)
{
    int i = blockIdx.x * 256 + threadIdx.x;
    if (i >= n4) return;
    float4 v = ((const float4*)in)[i];
    bh4 s;
    s[0] = f2b(v.x); s[1] = f2b(v.y); s[2] = f2b(v.z); s[3] = f2b(v.w);
    ((bh4*)out)[i] = s;
}

// ---------------- pack W[K][N] f32 -> bf16 MFMA-fragment order ----------------
__global__ __launch_bounds__(256) void pack_w(
    const float* __restrict__ W, short* __restrict__ out, int K, int N)
{
    int o = blockIdx.x * 256 + threadIdx.x;
    if (o >= K * N) return;
    int j    = o & 7;
    int lane = (o >> 3) & 63;
    int rest = o >> 9;
    int KK = K >> 5;
    int kk = rest % KK;
    int tile = rest / KK;
    int k = kk * 32 + (lane >> 4) * 8 + j;
    int n = tile * 16 + (lane & 15);
    out[o] = f2b(W[(size_t)k * N + n]);
}

// ---------------- CSR build: bucket histogram (LDS-aggregated) ----------------
__global__ __launch_bounds__(256) void bhist_kernel(
    const int* __restrict__ eu, const int* __restrict__ ei,
    int* __restrict__ bcu, int* __restrict__ bci,
    int E, int shu, int shi, int nbu, int nbi)
{
    __shared__ int hu[160], hi[160];
    int t = threadIdx.x;
    int base = blockIdx.x * 4096;
    if (t < 160) { hu[t] = 0; hi[t] = 0; }
    __syncthreads();
    int n = min(4096, E - base);
#pragma unroll 4
    for (int k = 0; k < 16; ++k) {
        int idx = k * 256 + t;
        if (idx < n) {
            atomicAdd(&hu[eu[base + idx] >> shu], 1);
            atomicAdd(&hi[ei[base + idx] >> shi], 1);
        }
    }
    __syncthreads();
    if (t < nbu && hu[t]) atomicAdd(&bcu[t], hu[t]);
    if (t < nbi && hi[t]) atomicAdd(&bci[t], hi[t]);
}

// ---------------- CSR build: bucket base scan ----------------
__global__ __launch_bounds__(256) void binit_kernel(
    const int* __restrict__ bcu, int* __restrict__ gcu, int* __restrict__ bbu, int nbu,
    const int* __restrict__ bci, int* __restrict__ gci, int* __restrict__ bbi, int nbi,
    int E)
{
    int t = threadIdx.x;
    {
        int v = (t < nbu) ? bcu[t] : 0;
        int ex = blk_excl_scan(v, t);
        if (t < nbu) { gcu[t] = ex; bbu[t] = ex; }
        if (t == 0) bbu[nbu] = E;
    }
    __syncthreads();
    {
        int v = (t < nbi) ? bci[t] : 0;
        int ex = blk_excl_scan(v, t);
        if (t < nbi) { gci[t] = ex; bbi[t] = ex; }
        if (t == 0) bbi[nbi] = E;
    }
}

// ---------------- CSR build: partition edges into buckets (both sides) ----------------
__global__ __launch_bounds__(256) void partition_kernel(
    const int* __restrict__ eu, const int* __restrict__ ei,
    int* __restrict__ gcu, int* __restrict__ gci,
    uint2* __restrict__ ebu, uint2* __restrict__ ebi,
    int E, int shu, int shi, int nbu, int nbi)
{
    __shared__ int hu[160], hi[160];
    int t = threadIdx.x;
    int base = blockIdx.x * 4096;
    if (t < 160) { hu[t] = 0; hi[t] = 0; }
    __syncthreads();
    int n = min(4096, E - base);
    int us[16], is_[16];
#pragma unroll 4
    for (int k = 0; k < 16; ++k) {
        int idx = k * 256 + t;
        if (idx < n) {
            us[k] = eu[base + idx];
            is_[k] = ei[base + idx];
            atomicAdd(&hu[us[k] >> shu], 1);
            atomicAdd(&hi[is_[k] >> shi], 1);
        } else us[k] = -1;
    }
    __syncthreads();
    if (t < nbu) { int c = hu[t]; hu[t] = c ? atomicAdd(&gcu[t], c) : 0; }
    if (t < nbi) { int c = hi[t]; hi[t] = c ? atomicAdd(&gci[t], c) : 0; }
    __syncthreads();
#pragma unroll 4
    for (int k = 0; k < 16; ++k) {
        if (us[k] >= 0) {
            int p1 = atomicAdd(&hu[us[k] >> shu], 1);
            ebu[p1] = make_uint2((unsigned)us[k], (unsigned)is_[k]);
            int p2 = atomicAdd(&hi[is_[k] >> shi], 1);
            ebi[p2] = make_uint2((unsigned)is_[k], (unsigned)us[k]);
        }
    }
}

// ---------------- CSR build: per-bucket offsets + adjacency (LDS-local) ----------------
__global__ __launch_bounds__(256) void fill2_kernel(
    const uint2* __restrict__ ebuf, const int* __restrict__ bbase,
    int* __restrict__ off, int* __restrict__ end_, int* __restrict__ adj,
    int span_sh, int nrows)
{
    __shared__ int lcnt[512];
    __shared__ int lcur[512];
    int t = threadIdx.x;
    int b = blockIdx.x;
    int rbase = b << span_sh;
    int span = min(1 << span_sh, nrows - rbase);
    int regbeg = bbase[b], regend = bbase[b + 1];
    for (int j = t; j < span; j += 256) lcnt[j] = 0;
    __syncthreads();
    for (int e = regbeg + t; e < regend; e += 256)
        atomicAdd(&lcnt[ebuf[e].x - rbase], 1);
    __syncthreads();
    int c0 = (2 * t < span) ? lcnt[2 * t] : 0;
    int c1 = (2 * t + 1 < span) ? lcnt[2 * t + 1] : 0;
    int ex = blk_excl_scan(c0 + c1, t);
    if (2 * t < span) {
        int beg = regbeg + ex;
        off[rbase + 2 * t] = beg;
        end_[rbase + 2 * t] = beg + c0;
        lcur[2 * t] = beg;
    }
    if (2 * t + 1 < span) {
        int beg = regbeg + ex + c0;
        off[rbase + 2 * t + 1] = beg;
        end_[rbase + 2 * t + 1] = beg + c1;
        lcur[2 * t + 1] = beg;
    }
    __syncthreads();
    for (int e = regbeg + t; e < regend; e += 256) {
        uint2 p = ebuf[e];
        int slot = atomicAdd(&lcur[p.x - rbase], 1);
        adj[slot] = (int)p.y;
    }
}

// ---------------- gathers (bf16 in, bf16 out) ----------------
__global__ __launch_bounds__(256) void gather_u_kernel(
    const short* __restrict__ iemb,
    const int* __restrict__ off, const int* __restrict__ end_,
    const int* __restrict__ adj, short* __restrict__ nu, int U)
{
    int wid = (blockIdx.x * 256 + threadIdx.x) >> 6;
    if (wid >= U) return;
    int lane = threadIdx.x & 63;
    int beg = off[wid], end = end_[wid];
    float ax = 0.f, ay = 0.f;
    int j = beg;
    for (; j + 3 < end; j += 4) {
        unsigned a = *(const unsigned*)(iemb + (size_t)adj[j]     * D_ + lane * 2);
        unsigned b = *(const unsigned*)(iemb + (size_t)adj[j + 1] * D_ + lane * 2);
        unsigned c = *(const unsigned*)(iemb + (size_t)adj[j + 2] * D_ + lane * 2);
        unsigned d = *(const unsigned*)(iemb + (size_t)adj[j + 3] * D_ + lane * 2);
        ax += b2f((short)(a & 0xffff)) + b2f((short)(b & 0xffff))
            + b2f((short)(c & 0xffff)) + b2f((short)(d & 0xffff));
        ay += b2f((short)(a >> 16)) + b2f((short)(b >> 16))
            + b2f((short)(c >> 16)) + b2f((short)(d >> 16));
    }
    for (; j < end; ++j) {
        unsigned a = *(const unsigned*)(iemb + (size_t)adj[j] * D_ + lane * 2);
        ax += b2f((short)(a & 0xffff));
        ay += b2f((short)(a >> 16));
    }
    unsigned o = ((unsigned)(unsigned short)f2b(ay) << 16) | (unsigned short)(unsigned)f2b(ax);
    *(unsigned*)(nu + (size_t)wid * D_ + lane * 2) = o;
}

__global__ __launch_bounds__(256) void gather_i_kernel(
    const short* __restrict__ ua, const short* __restrict__ ub,
    const int* __restrict__ off, const int* __restrict__ end_,
    const int* __restrict__ adj, short* __restrict__ ni, int I)
{
    int wid = (blockIdx.x * 256 + threadIdx.x) >> 6;
    if (wid >= I) return;
    int lane = threadIdx.x & 63;
    int beg = off[wid], end = end_[wid];
    float ax = 0.f, ay = 0.f;
    int j = beg;
    for (; j + 1 < end; j += 2) {
        size_t r0 = (size_t)adj[j] * D_ + lane * 2;
        size_t r1 = (size_t)adj[j + 1] * D_ + lane * 2;
        unsigned a0 = *(const unsigned*)(ua + r0);
        unsigned b0 = *(const unsigned*)(ub + r0);
        unsigned a1 = *(const unsigned*)(ua + r1);
        unsigned b1 = *(const unsigned*)(ub + r1);
        ax += 0.5f * (b2f((short)(a0 & 0xffff)) + b2f((short)(b0 & 0xffff)))
            + 0.5f * (b2f((short)(a1 & 0xffff)) + b2f((short)(b1 & 0xffff)));
        ay += 0.5f * (b2f((short)(a0 >> 16)) + b2f((short)(b0 >> 16)))
            + 0.5f * (b2f((short)(a1 >> 16)) + b2f((short)(b1 >> 16)));
    }
    if (j < end) {
        size_t r0 = (size_t)adj[j] * D_ + lane * 2;
        unsigned a0 = *(const unsigned*)(ua + r0);
        unsigned b0 = *(const unsigned*)(ub + r0);
        ax += 0.5f * (b2f((short)(a0 & 0xffff)) + b2f((short)(b0 & 0xffff)));
        ay += 0.5f * (b2f((short)(a0 >> 16)) + b2f((short)(b0 >> 16)));
    }
    unsigned o = ((unsigned)(unsigned short)f2b(ay) << 16) | (unsigned short)(unsigned)f2b(ax);
    *(unsigned*)(ni + (size_t)wid * D_ + lane * 2) = o;
}

// ---------------- fused gemm + MLP + norm + bias-colsum; y out as bf16 ----------------
template<int KCAT, int NARR>
__global__ __launch_bounds__(256, 3) void fused_mlp(
    const short* __restrict__ A0, const short* __restrict__ A1,
    const short* __restrict__ A2, const short* __restrict__ A3,
    const short* __restrict__ Wg, const float* __restrict__ bg,
    const short* __restrict__ W1p, const float* __restrict__ b1,
    const short* __restrict__ W2p, const float* __restrict__ b2,
    const short* __restrict__ W3p, const float* __restrict__ b3,
    short* __restrict__ Ybf, float* __restrict__ bsum)
{
    __shared__ char pool[47104];
    __shared__ float wred[4][16];
    __shared__ float nrms[16];

    short* x2 = (short*)pool;
    short* xc = (short*)(pool + 4096);
    short* h1 = (short*)(pool + 4096);
    short* h2 = (short*)(pool + 45056);
    short* yb = (short*)pool;

    const int t = threadIdx.x;
    const int l = t & 63;
    const int w = t >> 6;
    const int lr = l & 15;
    const int lg = l >> 4;
    const size_t rb0 = (size_t)blockIdx.x * 16;

    constexpr int CH_ROW = KCAT / 8;
    constexpr int NITER = (16 * CH_ROW) / 256;
#pragma unroll
    for (int j = 0; j < NITER; ++j) {
        int idx = j * 256 + t;
        int row = idx / CH_ROW;
        int slot = idx % CH_ROW;
        int a = slot >> 4, cs = slot & 15;
        const short* src = (NARR == 4) ? (a == 0 ? A0 : a == 1 ? A1 : a == 2 ? A2 : A3)
                                       : (a == 0 ? A0 : A1);
        bh8 v = *(const bh8*)(src + (rb0 + row) * D_ + cs * 8);
        int sl2 = slot ^ (row & 7);
        *(bh8*)(xc + row * KCAT + sl2 * 8) = v;
    }
    __syncthreads();

    {
        constexpr int KK_G = KCAT / 32;
        f32x4 accA0 = {0,0,0,0}, accB0 = accA0, accA1 = accA0, accB1 = accA0;
#pragma unroll 4
        for (int kk = 0; kk < KK_G; ++kk) {
            int slot = kk * 4 + lg;
            bh8 af = *(const bh8*)(xc + lr * KCAT + (slot ^ (lr & 7)) * 8);
            bh8 b0 = *(const bh8*)(Wg + (((size_t)(2 * w)     * KK_G + kk) * 64 + l) * 8);
            bh8 b1v = *(const bh8*)(Wg + (((size_t)(2 * w + 1) * KK_G + kk) * 64 + l) * 8);
            if (kk & 1) { accB0 = mfma16(af, b0, accB0); accB1 = mfma16(af, b1v, accB1); }
            else        { accA0 = mfma16(af, b0, accA0); accA1 = mfma16(af, b1v, accA1); }
        }
#pragma unroll
        for (int r = 0; r < 4; ++r) {
            int row = lg * 4 + r;
            int c0 = (2 * w) * 16 + lr;
            int c1 = c0 + 16;
            x2[row * 128 + (((c0 >> 3) ^ (row & 7)) * 8) + (l & 7)] = f2b(accA0[r] + accB0[r] + bg[c0]);
            x2[row * 128 + (((c1 >> 3) ^ (row & 7)) * 8) + (l & 7)] = f2b(accA1[r] + accB1[r] + bg[c1]);
        }
    }
    __syncthreads();

    {
        bh8 a1f[4];
#pragma unroll
        for (int kk = 0; kk < 4; ++kk) {
            int slot = kk * 4 + lg;
            a1f[kk] = *(const bh8*)(x2 + lr * 128 + (slot ^ (lr & 7)) * 8);
        }
#pragma unroll 2
        for (int tile = w * 20; tile < w * 20 + 20; ++tile) {
            float bv = b1[tile * 16 + lr];
            f32x4 acc = {bv, bv, bv, bv};
#pragma unroll
            for (int kk = 0; kk < 4; ++kk) {
                bh8 bf_ = *(const bh8*)(W1p + (((size_t)tile * 4 + kk) * 64 + l) * 8);
                acc = mfma16(a1f[kk], bf_, acc);
            }
#pragma unroll
            for (int r = 0; r < 4; ++r) {
                int row = lg * 4 + r;
                int col = tile * 16 + lr;
                h1[row * 1280 + (((col >> 3) ^ (row & 7)) * 8) + (l & 7)] = f2b(tanh_fast(acc[r]));
            }
        }
    }
    __syncthreads();

    {
        float bv = b2[w * 16 + lr];
        f32x4 accA = {bv, bv, bv, bv}, accB = {0,0,0,0};
#pragma unroll 4
        for (int kk = 0; kk < 40; ++kk) {
            int slot = kk * 4 + lg;
            bh8 af = *(const bh8*)(h1 + lr * 1280 + (slot ^ (lr & 7)) * 8);
            bh8 bf_ = *(const bh8*)(W2p + (((size_t)w * 40 + kk) * 64 + l) * 8);
            if (kk & 1) accB = mfma16(af, bf_, accB);
            else        accA = mfma16(af, bf_, accA);
        }
#pragma unroll
        for (int r = 0; r < 4; ++r) {
            int row = lg * 4 + r;
            int col = w * 16 + lr;
            h2[row * 64 + (((col >> 3) ^ (row & 7)) * 8) + (l & 7)] = f2b(tanh_fast(accA[r] + accB[r]));
        }
    }
    __syncthreads();

    {
        bh8 a3[2];
#pragma unroll
        for (int kk = 0; kk < 2; ++kk) {
            int slot = kk * 4 + lg;
            a3[kk] = *(const bh8*)(h2 + lr * 64 + (slot ^ (lr & 7)) * 8);
        }
        float ssq[4] = {0.f, 0.f, 0.f, 0.f};
#pragma unroll 2
        for (int tile = w * 20; tile < w * 20 + 20; ++tile) {
            float bv = b3[tile * 16 + lr];
            f32x4 acc = {bv, bv, bv, bv};
            bh8 b0 = *(const bh8*)(W3p + (((size_t)tile * 2 + 0) * 64 + l) * 8);
            bh8 b1v = *(const bh8*)(W3p + (((size_t)tile * 2 + 1) * 64 + l) * 8);
            acc = mfma16(a3[0], b0, acc);
            acc = mfma16(a3[1], b1v, acc);
            bh4 pk;
#pragma unroll
            for (int r = 0; r < 4; ++r) {
                ssq[r] = fmaf(acc[r], acc[r], ssq[r]);
                pk[r] = f2b(acc[r]);
            }
            *(bh4*)(yb + tile * 260 + l * 4) = pk;
        }
#pragma unroll
        for (int off = 1; off < 16; off <<= 1) {
#pragma unroll
            for (int r = 0; r < 4; ++r) ssq[r] += __shfl_xor(ssq[r], off);
        }
        if (lr == 0) {
#pragma unroll
            for (int r = 0; r < 4; ++r) wred[w][lg * 4 + r] = ssq[r];
        }
    }
    __syncthreads();
    if (t < 16) {
        float s = wred[0][t] + wred[1][t] + wred[2][t] + wred[3][t];
        nrms[t] = 1.f / fmaxf(sqrtf(s), 1e-12f);
    }
    __syncthreads();

    {
        float csum[5] = {0.f, 0.f, 0.f, 0.f, 0.f};
        for (int row = 0; row < 16; ++row) {
            float nv = nrms[row];
            int lph = (row >> 2) << 4;
            int r = row & 3;
#pragma unroll
            for (int ch = 0; ch < 5; ++ch) {
                int c = ch * 256 + t;
                int tile = c >> 4;
                int lanep = lph | (c & 15);
                float v = b2f(yb[tile * 260 + lanep * 4 + r]) * nv;
                Ybf[(rb0 + row) * DK_ + c] = f2b(v);
                csum[ch] += v;
            }
        }
#pragma unroll
        for (int ch = 0; ch < 5; ++ch) atomicAdd(&bsum[ch * 256 + t], csum[ch]);
    }
}

// ---------------- softmax over D axis: metau [U][128][10], bf16 in -> f32 out ----------------
__global__ __launch_bounds__(64) void softmax_u_kernel(
    const short* __restrict__ Ab, const float* __restrict__ bsum, float invM,
    float* __restrict__ Out)
{
    __shared__ float rowb[DK_];
    int u = blockIdx.x;
    int t = threadIdx.x;
    size_t base = (size_t)u * DK_;
    for (int i = t; i < DK_ / 2; i += 64) {
        unsigned a = ((const unsigned*)(Ab + base))[i];
        float2 bv = ((const float2*)bsum)[i];
        rowb[2 * i]     = b2f((short)(a & 0xffff)) + bv.x * invM;
        rowb[2 * i + 1] = b2f((short)(a >> 16))    + bv.y * invM;
    }
    __syncthreads();
#pragma unroll 1
    for (int k = 0; k < K_; ++k) {
        float v0 = rowb[t * K_ + k];
        float v1 = rowb[(t + 64) * K_ + k];
        float m = fmaxf(v0, v1);
        for (int off = 32; off; off >>= 1) m = fmaxf(m, __shfl_xor(m, off));
        float e0 = expf(v0 - m), e1 = expf(v1 - m);
        float s = e0 + e1;
        for (int off = 32; off; off >>= 1) s += __shfl_xor(s, off);
        float rs = 1.f / s;
        rowb[t * K_ + k] = e0 * rs;
        rowb[(t + 64) * K_ + k] = e1 * rs;
    }
    __syncthreads();
    for (int i = t; i < DK_; i += 64) Out[base + i] = rowb[i];
}

// ---------------- softmax over K axis: metai [I][10][128], bf16 in -> f32 out ----------------
__global__ __launch_bounds__(128) void softmax_i_kernel(
    const short* __restrict__ Ab, const float* __restrict__ bsum, float invM,
    float* __restrict__ Out)
{
    int it = blockIdx.x;
    int t = threadIdx.x;
    size_t base = (size_t)it * DK_;
    float v[K_];
    float m = -1e30f;
#pragma unroll
    for (int k = 0; k < K_; ++k) {
        v[k] = b2f(Ab[base + k * D_ + t]) + bsum[k * D_ + t] * invM;
        m = fmaxf(m, v[k]);
    }
    float s = 0.f;
#pragma unroll
    for (int k = 0; k < K_; ++k) { v[k] = expf(v[k] - m); s += v[k]; }
    float rs = 1.f / s;
#pragma unroll
    for (int k = 0; k < K_; ++k) Out[base + k * D_ + t] = v[k] * rs;
}

extern "C" void kernel_launch(void* const* d_in, const int* in_sizes, int n_in,
                              void* d_out, int out_size, void* d_ws, size_t ws_size,
                              hipStream_t stream)
{
    const float* uemb_s   = (const float*)d_in[0];
    const float* iemb_s   = (const float*)d_in[1];
    const float* uemb_t   = (const float*)d_in[2];
    const float* u_emb_sp = (const float*)d_in[3];
    const int*   eu       = (const int*)d_in[4];
    const int*   ei       = (const int*)d_in[5];
    const float* Wu  = (const float*)d_in[6];
    const float* bu  = (const float*)d_in[7];
    const float* Wi  = (const float*)d_in[8];
    const float* bi  = (const float*)d_in[9];
    const float* m1w1 = (const float*)d_in[10];
    const float* m1b1 = (const float*)d_in[11];
    const float* m1w2 = (const float*)d_in[12];
    const float* m1b2 = (const float*)d_in[13];
    const float* m1w3 = (const float*)d_in[14];
    const float* m1b3 = (const float*)d_in[15];
    const float* m2w1 = (const float*)d_in[16];
    const float* m2b1 = (const float*)d_in[17];
    const float* m2w2 = (const float*)d_in[18];
    const float* m2b2 = (const float*)d_in[19];
    const float* m2w3 = (const float*)d_in[20];
    const float* m2b3 = (const float*)d_in[21];

    const int U = in_sizes[0] / D_;
    const int I = in_sizes[1] / D_;
    const int E = in_sizes[4];

    const int SHU = 9, SHI = 8;
    const int NBU = (U + 511) >> 9;
    const int NBI = (I + 255) >> 8;

    char* p = (char*)d_ws;
    auto alloc = [&](size_t bytes) { char* r = p; p += (bytes + 255) & ~(size_t)255; return r; };

    short* usb  = (short*)alloc((size_t)U * D_ * 2);
    short* utb  = (short*)alloc((size_t)U * D_ * 2);
    short* uspb = (short*)alloc((size_t)U * D_ * 2);
    short* isb  = (short*)alloc((size_t)I * D_ * 2);
    short* nub  = (short*)alloc((size_t)U * D_ * 2);
    short* nib  = (short*)alloc((size_t)I * D_ * 2);
    short* ybu  = (short*)alloc((size_t)U * DK_ * 2);
    short* ybi  = (short*)alloc((size_t)I * DK_ * 2);
    short* WgU  = (short*)alloc(512 * 128 * 2);
    short* WgI  = (short*)alloc(256 * 128 * 2);
    short* W1U  = (short*)alloc(128 * 1280 * 2);
    short* W2U  = (short*)alloc(1280 * 64 * 2);
    short* W3U  = (short*)alloc(64 * 1280 * 2);
    short* W1I  = (short*)alloc(128 * 1280 * 2);
    short* W2I  = (short*)alloc(1280 * 64 * 2);
    short* W3I  = (short*)alloc(64 * 1280 * 2);
    float* bsu  = (float*)alloc(DK_ * 4);
    float* bsi  = (float*)alloc(DK_ * 4);
    int* bcnt   = (int*)alloc(320 * 4);          // bcnt_u | bcnt_i
    int* bcnt_u = bcnt;
    int* bcnt_i = bcnt + 160;
    int* gcur_u = (int*)alloc(160 * 4);
    int* gcur_i = (int*)alloc(160 * 4);
    int* bbase_u = (int*)alloc(161 * 4);
    int* bbase_i = (int*)alloc(161 * 4);
    int* off_u  = (int*)alloc((size_t)U * 4);
    int* end_u  = (int*)alloc((size_t)U * 4);
    int* off_i  = (int*)alloc((size_t)I * 4);
    int* end_i  = (int*)alloc((size_t)I * 4);
    uint2* ebu  = (uint2*)alloc((size_t)E * 8);
    uint2* ebi  = (uint2*)alloc((size_t)E * 8);
    int* adj_u  = (int*)alloc((size_t)E * 4);
    int* adj_i  = (int*)alloc((size_t)E * 4);

    float* outu = (float*)d_out;
    float* outi = outu + (size_t)U * DK_;

    hipMemsetAsync(bcnt, 0, 320 * 4, stream);
    hipMemsetAsync(bsu, 0, DK_ * 4, stream);
    hipMemsetAsync(bsi, 0, DK_ * 4, stream);

    // bf16 conversions
    int n4u = U * D_ / 4, n4i = I * D_ / 4;
    cvt_bf16<<<(n4u + 255) / 256, 256, 0, stream>>>(uemb_s,   usb,  n4u);
    cvt_bf16<<<(n4u + 255) / 256, 256, 0, stream>>>(uemb_t,   utb,  n4u);
    cvt_bf16<<<(n4u + 255) / 256, 256, 0, stream>>>(u_emb_sp, uspb, n4u);
    cvt_bf16<<<(n4i + 255) / 256, 256, 0, stream>>>(iemb_s,   isb,  n4i);

    // weight packing
    auto packW = [&](const float* W, short* o, int K, int N) {
        pack_w<<<(K * N + 255) / 256, 256, 0, stream>>>(W, o, K, N);
    };
    packW(Wu,   WgU, 512, 128);
    packW(Wi,   WgI, 256, 128);
    packW(m1w1, W1U, 128, 1280);
    packW(m1w2, W2U, 1280, 64);
    packW(m1w3, W3U, 64, 1280);
    packW(m2w1, W1I, 128, 1280);
    packW(m2w2, W2I, 1280, 64);
    packW(m2w3, W3I, 64, 1280);

    // CSR: bucket hist -> bases -> partition -> per-bucket fill
    int pb = (E + 4095) / 4096;
    bhist_kernel<<<pb, 256, 0, stream>>>(eu, ei, bcnt_u, bcnt_i, E, SHU, SHI, NBU, NBI);
    binit_kernel<<<1, 256, 0, stream>>>(bcnt_u, gcur_u, bbase_u, NBU,
                                        bcnt_i, gcur_i, bbase_i, NBI, E);
    partition_kernel<<<pb, 256, 0, stream>>>(eu, ei, gcur_u, gcur_i, ebu, ebi,
                                             E, SHU, SHI, NBU, NBI);
    fill2_kernel<<<NBU, 256, 0, stream>>>(ebu, bbase_u, off_u, end_u, adj_u, SHU, U);
    fill2_kernel<<<NBI, 256, 0, stream>>>(ebi, bbase_i, off_i, end_i, adj_i, SHI, I);

    // gathers
    gather_u_kernel<<<(U + 3) / 4, 256, 0, stream>>>(isb, off_u, end_u, adj_u, nub, U);
    gather_i_kernel<<<(I + 3) / 4, 256, 0, stream>>>(usb, uspb, off_i, end_i, adj_i, nib, I);

    // fused gemm + MLP + norm + colsum -> bf16 y in ws
    fused_mlp<512, 4><<<U / 16, 256, 0, stream>>>(
        usb, utb, uspb, nub, WgU, bu, W1U, m1b1, W2U, m1b2, W3U, m1b3, ybu, bsu);
    fused_mlp<256, 2><<<I / 16, 256, 0, stream>>>(
        isb, nib, nullptr, nullptr, WgI, bi, W1I, m2b1, W2I, m2b2, W3I, m2b3, ybi, bsi);

    // softmax with mean bias: bf16 in, f32 out
    softmax_u_kernel<<<U, 64, 0, stream>>>(ybu, bsu, 1.0f / (float)U, outu);
    softmax_i_kernel<<<I, 128, 0, stream>>>(ybi, bsi, 1.0f / (float)I, outi);
}

// Round 6
// 931.174 us; speedup vs baseline: 14.5767x; 1.0854x over previous
//
#include <hip/hip_runtime.h>
#include <hip/hip_bf16.h>

#define D_ 128
#define DK_ 1280
#define K_ 10

typedef __attribute__((ext_vector_type(8))) short bh8;   // 8 bf16 = 4 VGPR (MFMA A/B frag)
typedef __attribute__((ext_vector_type(4))) short bh4;
typedef __attribute__((ext_vector_type(4))) float f32x4; // MFMA C/D frag

__device__ __forceinline__ short f2b(float f) {
    unsigned u = __builtin_bit_cast(unsigned, f);
    u += 0x7fffu + ((u >> 16) & 1u);          // RNE
    return (short)(u >> 16);
}
__device__ __forceinline__ float b2f(short s) {
    unsigned u = ((unsigned)(unsigned short)s) << 16;
    return __builtin_bit_cast(float, u);
}
__device__ __forceinline__ float tanh_fast(float x) {
    float e = __expf(2.f * x);
    return 1.f - __fdividef(2.f, e + 1.f);    // exact at +-inf, no NaN
}
__device__ __forceinline__ f32x4 mfma16(bh8 a, bh8 b, f32x4 c) {
    return __builtin_amdgcn_mfma_f32_16x16x32_bf16(a, b, c, 0, 0, 0);
}

// block-exclusive scan of one int per thread (256 threads)
__device__ __forceinline__ int blk_excl_scan(int v, int t) {
    __shared__ int wp[4];
    int lane = t & 63, w = t >> 6;
    int s = v;
    for (int o = 1; o < 64; o <<= 1) {
        int pv = __shfl_up(s, o);
        if (lane >= o) s += pv;
    }
    if (lane == 63) wp[w] = s;
    __syncthreads();
    if (t == 0) {
        int a = 0;
#pragma unroll
        for (int k = 0; k < 4; ++k) { int x = wp[k]; wp[k] = a; a += x; }
    }
    __syncthreads();
    int r = s - v + wp[w];
    __syncthreads();
    return r;
}

// ---------------- fused f32->bf16 conversions + uavg ----------------
__global__ __launch_bounds__(256) void cvt_all(
    const float* __restrict__ us, const float* __restrict__ ut,
    const float* __restrict__ usp, const float* __restrict__ is_,
    short* __restrict__ usb, short* __restrict__ utb,
    short* __restrict__ uspb, short* __restrict__ uavg, short* __restrict__ isb,
    int n4u, int n4i)
{
    int i = blockIdx.x * 256 + threadIdx.x;
    if (i < n4u) {
        float4 a = ((const float4*)us)[i];
        float4 b = ((const float4*)ut)[i];
        float4 c = ((const float4*)usp)[i];
        bh4 sa, sb, sc, sv;
        sa[0] = f2b(a.x); sa[1] = f2b(a.y); sa[2] = f2b(a.z); sa[3] = f2b(a.w);
        sb[0] = f2b(b.x); sb[1] = f2b(b.y); sb[2] = f2b(b.z); sb[3] = f2b(b.w);
        sc[0] = f2b(c.x); sc[1] = f2b(c.y); sc[2] = f2b(c.z); sc[3] = f2b(c.w);
        sv[0] = f2b(0.5f * (a.x + c.x)); sv[1] = f2b(0.5f * (a.y + c.y));
        sv[2] = f2b(0.5f * (a.z + c.z)); sv[3] = f2b(0.5f * (a.w + c.w));
        ((bh4*)usb)[i] = sa; ((bh4*)utb)[i] = sb;
        ((bh4*)uspb)[i] = sc; ((bh4*)uavg)[i] = sv;
    } else if (i < n4u + n4i) {
        int j = i - n4u;
        float4 v = ((const float4*)is_)[j];
        bh4 s;
        s[0] = f2b(v.x); s[1] = f2b(v.y); s[2] = f2b(v.z); s[3] = f2b(v.w);
        ((bh4*)isb)[j] = s;
    }
}

// ---------------- pack all weights: W[K][N] f32 -> bf16 MFMA-fragment order ----------------
struct PackArgs {
    const float* W[8];
    short* o[8];
    int K[8];
    int N[8];
};
__global__ __launch_bounds__(256) void pack_all(PackArgs pa)
{
    int seg = blockIdx.y;
    int K = pa.K[seg], N = pa.N[seg];
    int total = K * N;
    int o = blockIdx.x * 256 + threadIdx.x;
    if (o >= total) return;
    const float* W = pa.W[seg];
    short* out = pa.o[seg];
    int j    = o & 7;
    int lane = (o >> 3) & 63;
    int rest = o >> 9;
    int KK = K >> 5;
    int kk = rest % KK;
    int tile = rest / KK;
    int k = kk * 32 + (lane >> 4) * 8 + j;
    int n = tile * 16 + (lane & 15);
    out[o] = f2b(W[(size_t)k * N + n]);
}

// ---------------- CSR build: bucket histogram (LDS-aggregated) ----------------
__global__ __launch_bounds__(256) void bhist_kernel(
    const int* __restrict__ eu, const int* __restrict__ ei,
    int* __restrict__ bcu, int* __restrict__ bci,
    int E, int shu, int shi, int nbu, int nbi)
{
    __shared__ int hu[160], hi[160];
    int t = threadIdx.x;
    int base = blockIdx.x * 4096;
    if (t < 160) { hu[t] = 0; hi[t] = 0; }
    __syncthreads();
    int n = min(4096, E - base);
#pragma unroll 4
    for (int k = 0; k < 16; ++k) {
        int idx = k * 256 + t;
        if (idx < n) {
            atomicAdd(&hu[eu[base + idx] >> shu], 1);
            atomicAdd(&hi[ei[base + idx] >> shi], 1);
        }
    }
    __syncthreads();
    if (t < nbu && hu[t]) atomicAdd(&bcu[t], hu[t]);
    if (t < nbi && hi[t]) atomicAdd(&bci[t], hi[t]);
}

// ---------------- CSR build: bucket base scan ----------------
__global__ __launch_bounds__(256) void binit_kernel(
    const int* __restrict__ bcu, int* __restrict__ gcu, int* __restrict__ bbu, int nbu,
    const int* __restrict__ bci, int* __restrict__ gci, int* __restrict__ bbi, int nbi,
    int E)
{
    int t = threadIdx.x;
    {
        int v = (t < nbu) ? bcu[t] : 0;
        int ex = blk_excl_scan(v, t);
        if (t < nbu) { gcu[t] = ex; bbu[t] = ex; }
        if (t == 0) bbu[nbu] = E;
    }
    __syncthreads();
    {
        int v = (t < nbi) ? bci[t] : 0;
        int ex = blk_excl_scan(v, t);
        if (t < nbi) { gci[t] = ex; bbi[t] = ex; }
        if (t == 0) bbi[nbi] = E;
    }
}

// ---------------- CSR build: partition edges into buckets (both sides) ----------------
__global__ __launch_bounds__(256) void partition_kernel(
    const int* __restrict__ eu, const int* __restrict__ ei,
    int* __restrict__ gcu, int* __restrict__ gci,
    uint2* __restrict__ ebu, uint2* __restrict__ ebi,
    int E, int shu, int shi, int nbu, int nbi)
{
    __shared__ int hu[160], hi[160];
    int t = threadIdx.x;
    int base = blockIdx.x * 4096;
    if (t < 160) { hu[t] = 0; hi[t] = 0; }
    __syncthreads();
    int n = min(4096, E - base);
    int us[16], is_[16];
#pragma unroll 4
    for (int k = 0; k < 16; ++k) {
        int idx = k * 256 + t;
        if (idx < n) {
            us[k] = eu[base + idx];
            is_[k] = ei[base + idx];
            atomicAdd(&hu[us[k] >> shu], 1);
            atomicAdd(&hi[is_[k] >> shi], 1);
        } else us[k] = -1;
    }
    __syncthreads();
    if (t < nbu) { int c = hu[t]; hu[t] = c ? atomicAdd(&gcu[t], c) : 0; }
    if (t < nbi) { int c = hi[t]; hi[t] = c ? atomicAdd(&gci[t], c) : 0; }
    __syncthreads();
#pragma unroll 4
    for (int k = 0; k < 16; ++k) {
        if (us[k] >= 0) {
            int p1 = atomicAdd(&hu[us[k] >> shu], 1);
            ebu[p1] = make_uint2((unsigned)us[k], (unsigned)is_[k]);
            int p2 = atomicAdd(&hi[is_[k] >> shi], 1);
            ebi[p2] = make_uint2((unsigned)is_[k], (unsigned)us[k]);
        }
    }
}

// ---------------- CSR build: per-bucket offsets + adjacency (LDS-local) ----------------
__global__ __launch_bounds__(256) void fill2_kernel(
    const uint2* __restrict__ ebuf, const int* __restrict__ bbase,
    int* __restrict__ off, int* __restrict__ end_, int* __restrict__ adj,
    int span_sh, int nrows)
{
    __shared__ int lcnt[512];
    __shared__ int lcur[512];
    int t = threadIdx.x;
    int b = blockIdx.x;
    int rbase = b << span_sh;
    int span = min(1 << span_sh, nrows - rbase);
    int regbeg = bbase[b], regend = bbase[b + 1];
    for (int j = t; j < span; j += 256) lcnt[j] = 0;
    __syncthreads();
    for (int e = regbeg + t; e < regend; e += 256)
        atomicAdd(&lcnt[ebuf[e].x - rbase], 1);
    __syncthreads();
    int c0 = (2 * t < span) ? lcnt[2 * t] : 0;
    int c1 = (2 * t + 1 < span) ? lcnt[2 * t + 1] : 0;
    int ex = blk_excl_scan(c0 + c1, t);
    if (2 * t < span) {
        int beg = regbeg + ex;
        off[rbase + 2 * t] = beg;
        end_[rbase + 2 * t] = beg + c0;
        lcur[2 * t] = beg;
    }
    if (2 * t + 1 < span) {
        int beg = regbeg + ex + c0;
        off[rbase + 2 * t + 1] = beg;
        end_[rbase + 2 * t + 1] = beg + c1;
        lcur[2 * t + 1] = beg;
    }
    __syncthreads();
    for (int e = regbeg + t; e < regend; e += 256) {
        uint2 p = ebuf[e];
        int slot = atomicAdd(&lcur[p.x - rbase], 1);
        adj[slot] = (int)p.y;
    }
}

// ---------------- gather: sum of emb rows over adjacency ----------------
__global__ __launch_bounds__(256) void gather_kernel(
    const short* __restrict__ emb,
    const int* __restrict__ off, const int* __restrict__ end_,
    const int* __restrict__ adj, short* __restrict__ out, int M)
{
    int wid = (blockIdx.x * 256 + threadIdx.x) >> 6;
    if (wid >= M) return;
    int lane = threadIdx.x & 63;
    int beg = off[wid], end = end_[wid];
    float ax = 0.f, ay = 0.f;
    int j = beg;
    for (; j + 3 < end; j += 4) {
        unsigned a = *(const unsigned*)(emb + (size_t)adj[j]     * D_ + lane * 2);
        unsigned b = *(const unsigned*)(emb + (size_t)adj[j + 1] * D_ + lane * 2);
        unsigned c = *(const unsigned*)(emb + (size_t)adj[j + 2] * D_ + lane * 2);
        unsigned d = *(const unsigned*)(emb + (size_t)adj[j + 3] * D_ + lane * 2);
        ax += b2f((short)(a & 0xffff)) + b2f((short)(b & 0xffff))
            + b2f((short)(c & 0xffff)) + b2f((short)(d & 0xffff));
        ay += b2f((short)(a >> 16)) + b2f((short)(b >> 16))
            + b2f((short)(c >> 16)) + b2f((short)(d >> 16));
    }
    for (; j < end; ++j) {
        unsigned a = *(const unsigned*)(emb + (size_t)adj[j] * D_ + lane * 2);
        ax += b2f((short)(a & 0xffff));
        ay += b2f((short)(a >> 16));
    }
    unsigned o = ((unsigned)(unsigned short)f2b(ay) << 16) | (unsigned short)(unsigned)f2b(ax);
    *(unsigned*)(out + (size_t)wid * D_ + lane * 2) = o;
}

// ---------------- fused gemm + MLP + norm + bias-colsum; y out as bf16 ----------------
template<int KCAT, int NARR>
__global__ __launch_bounds__(256, 3) void fused_mlp(
    const short* __restrict__ A0, const short* __restrict__ A1,
    const short* __restrict__ A2, const short* __restrict__ A3,
    const short* __restrict__ Wg, const float* __restrict__ bg,
    const short* __restrict__ W1p, const float* __restrict__ b1,
    const short* __restrict__ W2p, const float* __restrict__ b2,
    const short* __restrict__ W3p, const float* __restrict__ b3,
    short* __restrict__ Ybf, float* __restrict__ bsum)
{
    __shared__ char pool[47104];
    __shared__ float wred[4][16];
    __shared__ float nrms[16];

    short* x2 = (short*)pool;
    short* xc = (short*)(pool + 4096);
    short* h1 = (short*)(pool + 4096);
    short* h2 = (short*)(pool + 45056);
    short* yb = (short*)pool;

    const int t = threadIdx.x;
    const int l = t & 63;
    const int w = t >> 6;
    const int lr = l & 15;
    const int lg = l >> 4;
    const size_t rb0 = (size_t)blockIdx.x * 16;

    constexpr int CH_ROW = KCAT / 8;
    constexpr int NITER = (16 * CH_ROW) / 256;
#pragma unroll
    for (int j = 0; j < NITER; ++j) {
        int idx = j * 256 + t;
        int row = idx / CH_ROW;
        int slot = idx % CH_ROW;
        int a = slot >> 4, cs = slot & 15;
        const short* src = (NARR == 4) ? (a == 0 ? A0 : a == 1 ? A1 : a == 2 ? A2 : A3)
                                       : (a == 0 ? A0 : A1);
        bh8 v = *(const bh8*)(src + (rb0 + row) * D_ + cs * 8);
        int sl2 = slot ^ (row & 7);
        *(bh8*)(xc + row * KCAT + sl2 * 8) = v;
    }
    __syncthreads();

    {
        constexpr int KK_G = KCAT / 32;
        f32x4 accA0 = {0,0,0,0}, accB0 = accA0, accA1 = accA0, accB1 = accA0;
#pragma unroll 4
        for (int kk = 0; kk < KK_G; ++kk) {
            int slot = kk * 4 + lg;
            bh8 af = *(const bh8*)(xc + lr * KCAT + (slot ^ (lr & 7)) * 8);
            bh8 b0 = *(const bh8*)(Wg + (((size_t)(2 * w)     * KK_G + kk) * 64 + l) * 8);
            bh8 b1v = *(const bh8*)(Wg + (((size_t)(2 * w + 1) * KK_G + kk) * 64 + l) * 8);
            if (kk & 1) { accB0 = mfma16(af, b0, accB0); accB1 = mfma16(af, b1v, accB1); }
            else        { accA0 = mfma16(af, b0, accA0); accA1 = mfma16(af, b1v, accA1); }
        }
#pragma unroll
        for (int r = 0; r < 4; ++r) {
            int row = lg * 4 + r;
            int c0 = (2 * w) * 16 + lr;
            int c1 = c0 + 16;
            x2[row * 128 + (((c0 >> 3) ^ (row & 7)) * 8) + (l & 7)] = f2b(accA0[r] + accB0[r] + bg[c0]);
            x2[row * 128 + (((c1 >> 3) ^ (row & 7)) * 8) + (l & 7)] = f2b(accA1[r] + accB1[r] + bg[c1]);
        }
    }
    __syncthreads();

    {
        bh8 a1f[4];
#pragma unroll
        for (int kk = 0; kk < 4; ++kk) {
            int slot = kk * 4 + lg;
            a1f[kk] = *(const bh8*)(x2 + lr * 128 + (slot ^ (lr & 7)) * 8);
        }
#pragma unroll 2
        for (int tile = w * 20; tile < w * 20 + 20; ++tile) {
            float bv = b1[tile * 16 + lr];
            f32x4 acc = {bv, bv, bv, bv};
#pragma unroll
            for (int kk = 0; kk < 4; ++kk) {
                bh8 bf_ = *(const bh8*)(W1p + (((size_t)tile * 4 + kk) * 64 + l) * 8);
                acc = mfma16(a1f[kk], bf_, acc);
            }
#pragma unroll
            for (int r = 0; r < 4; ++r) {
                int row = lg * 4 + r;
                int col = tile * 16 + lr;
                h1[row * 1280 + (((col >> 3) ^ (row & 7)) * 8) + (l & 7)] = f2b(tanh_fast(acc[r]));
            }
        }
    }
    __syncthreads();

    {
        float bv = b2[w * 16 + lr];
        f32x4 accA = {bv, bv, bv, bv}, accB = {0,0,0,0};
#pragma unroll 4
        for (int kk = 0; kk < 40; ++kk) {
            int slot = kk * 4 + lg;
            bh8 af = *(const bh8*)(h1 + lr * 1280 + (slot ^ (lr & 7)) * 8);
            bh8 bf_ = *(const bh8*)(W2p + (((size_t)w * 40 + kk) * 64 + l) * 8);
            if (kk & 1) accB = mfma16(af, bf_, accB);
            else        accA = mfma16(af, bf_, accA);
        }
#pragma unroll
        for (int r = 0; r < 4; ++r) {
            int row = lg * 4 + r;
            int col = w * 16 + lr;
            h2[row * 64 + (((col >> 3) ^ (row & 7)) * 8) + (l & 7)] = f2b(tanh_fast(accA[r] + accB[r]));
        }
    }
    __syncthreads();

    {
        bh8 a3[2];
#pragma unroll
        for (int kk = 0; kk < 2; ++kk) {
            int slot = kk * 4 + lg;
            a3[kk] = *(const bh8*)(h2 + lr * 64 + (slot ^ (lr & 7)) * 8);
        }
        float ssq[4] = {0.f, 0.f, 0.f, 0.f};
#pragma unroll 2
        for (int tile = w * 20; tile < w * 20 + 20; ++tile) {
            float bv = b3[tile * 16 + lr];
            f32x4 acc = {bv, bv, bv, bv};
            bh8 b0 = *(const bh8*)(W3p + (((size_t)tile * 2 + 0) * 64 + l) * 8);
            bh8 b1v = *(const bh8*)(W3p + (((size_t)tile * 2 + 1) * 64 + l) * 8);
            acc = mfma16(a3[0], b0, acc);
            acc = mfma16(a3[1], b1v, acc);
            bh4 pk;
#pragma unroll
            for (int r = 0; r < 4; ++r) {
                ssq[r] = fmaf(acc[r], acc[r], ssq[r]);
                pk[r] = f2b(acc[r]);
            }
            *(bh4*)(yb + tile * 260 + l * 4) = pk;
        }
#pragma unroll
        for (int off = 1; off < 16; off <<= 1) {
#pragma unroll
            for (int r = 0; r < 4; ++r) ssq[r] += __shfl_xor(ssq[r], off);
        }
        if (lr == 0) {
#pragma unroll
            for (int r = 0; r < 4; ++r) wred[w][lg * 4 + r] = ssq[r];
        }
    }
    __syncthreads();
    if (t < 16) {
        float s = wred[0][t] + wred[1][t] + wred[2][t] + wred[3][t];
        nrms[t] = 1.f / fmaxf(sqrtf(s), 1e-12f);
    }
    __syncthreads();

    {
        float csum[5] = {0.f, 0.f, 0.f, 0.f, 0.f};
        for (int row = 0; row < 16; ++row) {
            float nv = nrms[row];
            int lph = (row >> 2) << 4;
            int r = row & 3;
#pragma unroll
            for (int ch = 0; ch < 5; ++ch) {
                int c = ch * 256 + t;
                int tile = c >> 4;
                int lanep = lph | (c & 15);
                float v = b2f(yb[tile * 260 + lanep * 4 + r]) * nv;
                Ybf[(rb0 + row) * DK_ + c] = f2b(v);
                csum[ch] += v;
            }
        }
#pragma unroll
        for (int ch = 0; ch < 5; ++ch) atomicAdd(&bsum[ch * 256 + t], csum[ch]);
    }
}

// ---------------- softmax over D axis: metau [U][128][10], bf16 in -> f32 out ----------------
__global__ __launch_bounds__(64) void softmax_u_kernel(
    const short* __restrict__ Ab, const float* __restrict__ bsum, float invM,
    float* __restrict__ Out)
{
    __shared__ float rowb[DK_];
    int u = blockIdx.x;
    int t = threadIdx.x;
    size_t base = (size_t)u * DK_;
    for (int i = t; i < DK_ / 2; i += 64) {
        unsigned a = ((const unsigned*)(Ab + base))[i];
        float2 bv = ((const float2*)bsum)[i];
        rowb[2 * i]     = b2f((short)(a & 0xffff)) + bv.x * invM;
        rowb[2 * i + 1] = b2f((short)(a >> 16))    + bv.y * invM;
    }
    __syncthreads();
#pragma unroll 1
    for (int k = 0; k < K_; ++k) {
        float v0 = rowb[t * K_ + k];
        float v1 = rowb[(t + 64) * K_ + k];
        float m = fmaxf(v0, v1);
        for (int off = 32; off; off >>= 1) m = fmaxf(m, __shfl_xor(m, off));
        float e0 = expf(v0 - m), e1 = expf(v1 - m);
        float s = e0 + e1;
        for (int off = 32; off; off >>= 1) s += __shfl_xor(s, off);
        float rs = 1.f / s;
        rowb[t * K_ + k] = e0 * rs;
        rowb[(t + 64) * K_ + k] = e1 * rs;
    }
    __syncthreads();
    for (int i = t; i < DK_; i += 64) Out[base + i] = rowb[i];
}

// ---------------- softmax over K axis: metai [I][10][128], bf16 in -> f32 out ----------------
__global__ __launch_bounds__(128) void softmax_i_kernel(
    const short* __restrict__ Ab, const float* __restrict__ bsum, float invM,
    float* __restrict__ Out)
{
    int it = blockIdx.x;
    int t = threadIdx.x;
    size_t base = (size_t)it * DK_;
    float v[K_];
    float m = -1e30f;
#pragma unroll
    for (int k = 0; k < K_; ++k) {
        v[k] = b2f(Ab[base + k * D_ + t]) + bsum[k * D_ + t] * invM;
        m = fmaxf(m, v[k]);
    }
    float s = 0.f;
#pragma unroll
    for (int k = 0; k < K_; ++k) { v[k] = expf(v[k] - m); s += v[k]; }
    float rs = 1.f / s;
#pragma unroll
    for (int k = 0; k < K_; ++k) Out[base + k * D_ + t] = v[k] * rs;
}

extern "C" void kernel_launch(void* const* d_in, const int* in_sizes, int n_in,
                              void* d_out, int out_size, void* d_ws, size_t ws_size,
                              hipStream_t stream)
{
    const float* uemb_s   = (const float*)d_in[0];
    const float* iemb_s   = (const float*)d_in[1];
    const float* uemb_t   = (const float*)d_in[2];
    const float* u_emb_sp = (const float*)d_in[3];
    const int*   eu       = (const int*)d_in[4];
    const int*   ei       = (const int*)d_in[5];
    const float* Wu  = (const float*)d_in[6];
    const float* bu  = (const float*)d_in[7];
    const float* Wi  = (const float*)d_in[8];
    const float* bi  = (const float*)d_in[9];
    const float* m1w1 = (const float*)d_in[10];
    const float* m1b1 = (const float*)d_in[11];
    const float* m1w2 = (const float*)d_in[12];
    const float* m1b2 = (const float*)d_in[13];
    const float* m1w3 = (const float*)d_in[14];
    const float* m1b3 = (const float*)d_in[15];
    const float* m2w1 = (const float*)d_in[16];
    const float* m2b1 = (const float*)d_in[17];
    const float* m2w2 = (const float*)d_in[18];
    const float* m2b2 = (const float*)d_in[19];
    const float* m2w3 = (const float*)d_in[20];
    const float* m2b3 = (const float*)d_in[21];

    const int U = in_sizes[0] / D_;
    const int I = in_sizes[1] / D_;
    const int E = in_sizes[4];

    const int SHU = 9, SHI = 8;
    const int NBU = (U + 511) >> 9;
    const int NBI = (I + 255) >> 8;

    char* p = (char*)d_ws;
    auto alloc = [&](size_t bytes) { char* r = p; p += (bytes + 255) & ~(size_t)255; return r; };

    short* usb  = (short*)alloc((size_t)U * D_ * 2);
    short* utb  = (short*)alloc((size_t)U * D_ * 2);
    short* uspb = (short*)alloc((size_t)U * D_ * 2);
    short* uavg = (short*)alloc((size_t)U * D_ * 2);
    short* isb  = (short*)alloc((size_t)I * D_ * 2);
    short* nub  = (short*)alloc((size_t)U * D_ * 2);
    short* nib  = (short*)alloc((size_t)I * D_ * 2);
    short* ybu  = (short*)alloc((size_t)U * DK_ * 2);
    short* ybi  = (short*)alloc((size_t)I * DK_ * 2);
    short* WgU  = (short*)alloc(512 * 128 * 2);
    short* WgI  = (short*)alloc(256 * 128 * 2);
    short* W1U  = (short*)alloc(128 * 1280 * 2);
    short* W2U  = (short*)alloc(1280 * 64 * 2);
    short* W3U  = (short*)alloc(64 * 1280 * 2);
    short* W1I  = (short*)alloc(128 * 1280 * 2);
    short* W2I  = (short*)alloc(1280 * 64 * 2);
    short* W3I  = (short*)alloc(64 * 1280 * 2);
    float* bsu  = (float*)alloc(DK_ * 4);
    float* bsi  = (float*)alloc(DK_ * 4);
    int* bcnt   = (int*)alloc(320 * 4);          // bcnt_u | bcnt_i
    int* bcnt_u = bcnt;
    int* bcnt_i = bcnt + 160;
    int* gcur_u = (int*)alloc(160 * 4);
    int* gcur_i = (int*)alloc(160 * 4);
    int* bbase_u = (int*)alloc(161 * 4);
    int* bbase_i = (int*)alloc(161 * 4);
    int* off_u  = (int*)alloc((size_t)U * 4);
    int* end_u  = (int*)alloc((size_t)U * 4);
    int* off_i  = (int*)alloc((size_t)I * 4);
    int* end_i  = (int*)alloc((size_t)I * 4);
    uint2* ebu  = (uint2*)alloc((size_t)E * 8);
    uint2* ebi  = (uint2*)alloc((size_t)E * 8);
    int* adj_u  = (int*)alloc((size_t)E * 4);
    int* adj_i  = (int*)alloc((size_t)E * 4);

    float* outu = (float*)d_out;
    float* outi = outu + (size_t)U * DK_;

    hipMemsetAsync(bcnt, 0, 320 * 4, stream);
    hipMemsetAsync(bsu, 0, DK_ * 4, stream);
    hipMemsetAsync(bsi, 0, DK_ * 4, stream);

    // fused bf16 conversions + uavg
    int n4u = U * D_ / 4, n4i = I * D_ / 4;
    cvt_all<<<(n4u + n4i + 255) / 256, 256, 0, stream>>>(
        uemb_s, uemb_t, u_emb_sp, iemb_s, usb, utb, uspb, uavg, isb, n4u, n4i);

    // pack all weights in one launch
    PackArgs pa;
    pa.W[0] = Wu;   pa.o[0] = WgU; pa.K[0] = 512;  pa.N[0] = 128;
    pa.W[1] = Wi;   pa.o[1] = WgI; pa.K[1] = 256;  pa.N[1] = 128;
    pa.W[2] = m1w1; pa.o[2] = W1U; pa.K[2] = 128;  pa.N[2] = 1280;
    pa.W[3] = m1w2; pa.o[3] = W2U; pa.K[3] = 1280; pa.N[3] = 64;
    pa.W[4] = m1w3; pa.o[4] = W3U; pa.K[4] = 64;   pa.N[4] = 1280;
    pa.W[5] = m2w1; pa.o[5] = W1I; pa.K[5] = 128;  pa.N[5] = 1280;
    pa.W[6] = m2w2; pa.o[6] = W2I; pa.K[6] = 1280; pa.N[6] = 64;
    pa.W[7] = m2w3; pa.o[7] = W3I; pa.K[7] = 64;   pa.N[7] = 1280;
    pack_all<<<dim3(640, 8), 256, 0, stream>>>(pa);

    // CSR: bucket hist -> bases -> partition -> per-bucket fill
    int pb = (E + 4095) / 4096;
    bhist_kernel<<<pb, 256, 0, stream>>>(eu, ei, bcnt_u, bcnt_i, E, SHU, SHI, NBU, NBI);
    binit_kernel<<<1, 256, 0, stream>>>(bcnt_u, gcur_u, bbase_u, NBU,
                                        bcnt_i, gcur_i, bbase_i, NBI, E);
    partition_kernel<<<pb, 256, 0, stream>>>(eu, ei, gcur_u, gcur_i, ebu, ebi,
                                             E, SHU, SHI, NBU, NBI);
    fill2_kernel<<<NBU, 256, 0, stream>>>(ebu, bbase_u, off_u, end_u, adj_u, SHU, U);
    fill2_kernel<<<NBI, 256, 0, stream>>>(ebi, bbase_i, off_i, end_i, adj_i, SHI, I);

    // gathers (i-side reads precomputed uavg: one row per edge)
    gather_kernel<<<(U + 3) / 4, 256, 0, stream>>>(isb,  off_u, end_u, adj_u, nub, U);
    gather_kernel<<<(I + 3) / 4, 256, 0, stream>>>(uavg, off_i, end_i, adj_i, nib, I);

    // fused gemm + MLP + norm + colsum -> bf16 y in ws
    fused_mlp<512, 4><<<U / 16, 256, 0, stream>>>(
        usb, utb, uspb, nub, WgU, bu, W1U, m1b1, W2U, m1b2, W3U, m1b3, ybu, bsu);
    fused_mlp<256, 2><<<I / 16, 256, 0, stream>>>(
        isb, nib, nullptr, nullptr, WgI, bi, W1I, m2b1, W2I, m2b2, W3I, m2b3, ybi, bsi);

    // softmax with mean bias: bf16 in, f32 out
    softmax_u_kernel<<<U, 64, 0, stream>>>(ybu, bsu, 1.0f / (float)U, outu);
    softmax_i_kernel<<<I, 128, 0, stream>>>(ybi, bsi, 1.0f / (float)I, outi);
}

// Round 7
// 880.403 us; speedup vs baseline: 15.4172x; 1.0577x over previous
//
#include <hip/hip_runtime.h>
#include <hip/hip_bf16.h>

#define D_ 128
#define DK_ 1280
#define K_ 10

typedef __attribute__((ext_vector_type(8))) short bh8;   // 8 bf16 = 4 VGPR (MFMA A/B frag)
typedef __attribute__((ext_vector_type(4))) short bh4;
typedef __attribute__((ext_vector_type(4))) float f32x4; // MFMA C/D frag

__device__ __forceinline__ short f2b(float f) {
    unsigned u = __builtin_bit_cast(unsigned, f);
    u += 0x7fffu + ((u >> 16) & 1u);          // RNE
    return (short)(u >> 16);
}
__device__ __forceinline__ float b2f(short s) {
    unsigned u = ((unsigned)(unsigned short)s) << 16;
    return __builtin_bit_cast(float, u);
}
__device__ __forceinline__ float tanh_fast(float x) {
    float e = __expf(2.f * x);
    return 1.f - __fdividef(2.f, e + 1.f);
}
__device__ __forceinline__ f32x4 mfma16(bh8 a, bh8 b, f32x4 c) {
    return __builtin_amdgcn_mfma_f32_16x16x32_bf16(a, b, c, 0, 0, 0);
}

// block-exclusive scan of one int per thread (256 threads)
__device__ __forceinline__ int blk_excl_scan(int v, int t) {
    __shared__ int wp[4];
    int lane = t & 63, w = t >> 6;
    int s = v;
    for (int o = 1; o < 64; o <<= 1) {
        int pv = __shfl_up(s, o);
        if (lane >= o) s += pv;
    }
    if (lane == 63) wp[w] = s;
    __syncthreads();
    if (t == 0) {
        int a = 0;
#pragma unroll
        for (int k = 0; k < 4; ++k) { int x = wp[k]; wp[k] = a; a += x; }
    }
    __syncthreads();
    int r = s - v + wp[w];
    __syncthreads();
    return r;
}

// ---------------- fused f32->bf16 conversions + uavg ----------------
__global__ __launch_bounds__(256) void cvt_all(
    const float* __restrict__ us, const float* __restrict__ ut,
    const float* __restrict__ usp, const float* __restrict__ is_,
    short* __restrict__ usb, short* __restrict__ utb,
    short* __restrict__ uspb, short* __restrict__ uavg, short* __restrict__ isb,
    int n4u, int n4i)
{
    int i = blockIdx.x * 256 + threadIdx.x;
    if (i < n4u) {
        float4 a = ((const float4*)us)[i];
        float4 b = ((const float4*)ut)[i];
        float4 c = ((const float4*)usp)[i];
        bh4 sa, sb, sc, sv;
        sa[0] = f2b(a.x); sa[1] = f2b(a.y); sa[2] = f2b(a.z); sa[3] = f2b(a.w);
        sb[0] = f2b(b.x); sb[1] = f2b(b.y); sb[2] = f2b(b.z); sb[3] = f2b(b.w);
        sc[0] = f2b(c.x); sc[1] = f2b(c.y); sc[2] = f2b(c.z); sc[3] = f2b(c.w);
        sv[0] = f2b(0.5f * (a.x + c.x)); sv[1] = f2b(0.5f * (a.y + c.y));
        sv[2] = f2b(0.5f * (a.z + c.z)); sv[3] = f2b(0.5f * (a.w + c.w));
        ((bh4*)usb)[i] = sa; ((bh4*)utb)[i] = sb;
        ((bh4*)uspb)[i] = sc; ((bh4*)uavg)[i] = sv;
    } else if (i < n4u + n4i) {
        int j = i - n4u;
        float4 v = ((const float4*)is_)[j];
        bh4 s;
        s[0] = f2b(v.x); s[1] = f2b(v.y); s[2] = f2b(v.z); s[3] = f2b(v.w);
        ((bh4*)isb)[j] = s;
    }
}

// ---------------- pack all weights: W[K][N] f32 -> bf16 MFMA-fragment order ----------------
struct PackArgs {
    const float* W[8];
    short* o[8];
    int K[8];
    int N[8];
};
__global__ __launch_bounds__(256) void pack_all(PackArgs pa)
{
    int seg = blockIdx.y;
    int K = pa.K[seg], N = pa.N[seg];
    int total = K * N;
    int o = blockIdx.x * 256 + threadIdx.x;
    if (o >= total) return;
    const float* W = pa.W[seg];
    short* out = pa.o[seg];
    int j    = o & 7;
    int lane = (o >> 3) & 63;
    int rest = o >> 9;
    int KK = K >> 5;
    int kk = rest % KK;
    int tile = rest / KK;
    int k = kk * 32 + (lane >> 4) * 8 + j;
    int n = tile * 16 + (lane & 15);
    out[o] = f2b(W[(size_t)k * N + n]);
}

// ---------------- CSR build: bucket histogram (LDS-aggregated) ----------------
__global__ __launch_bounds__(256) void bhist_kernel(
    const int* __restrict__ eu, const int* __restrict__ ei,
    int* __restrict__ bcu, int* __restrict__ bci,
    int E, int shu, int shi, int nbu, int nbi)
{
    __shared__ int hu[160], hi[160];
    int t = threadIdx.x;
    int base = blockIdx.x * 4096;
    if (t < 160) { hu[t] = 0; hi[t] = 0; }
    __syncthreads();
    int n = min(4096, E - base);
#pragma unroll 4
    for (int k = 0; k < 16; ++k) {
        int idx = k * 256 + t;
        if (idx < n) {
            atomicAdd(&hu[eu[base + idx] >> shu], 1);
            atomicAdd(&hi[ei[base + idx] >> shi], 1);
        }
    }
    __syncthreads();
    if (t < nbu && hu[t]) atomicAdd(&bcu[t], hu[t]);
    if (t < nbi && hi[t]) atomicAdd(&bci[t], hi[t]);
}

// ---------------- CSR build: bucket base scan ----------------
__global__ __launch_bounds__(256) void binit_kernel(
    const int* __restrict__ bcu, int* __restrict__ gcu, int* __restrict__ bbu, int nbu,
    const int* __restrict__ bci, int* __restrict__ gci, int* __restrict__ bbi, int nbi,
    int E)
{
    int t = threadIdx.x;
    {
        int v = (t < nbu) ? bcu[t] : 0;
        int ex = blk_excl_scan(v, t);
        if (t < nbu) { gcu[t] = ex; bbu[t] = ex; }
        if (t == 0) bbu[nbu] = E;
    }
    __syncthreads();
    {
        int v = (t < nbi) ? bci[t] : 0;
        int ex = blk_excl_scan(v, t);
        if (t < nbi) { gci[t] = ex; bbi[t] = ex; }
        if (t == 0) bbi[nbi] = E;
    }
}

// ---------------- CSR build: partition edges into buckets (both sides) ----------------
__global__ __launch_bounds__(256) void partition_kernel(
    const int* __restrict__ eu, const int* __restrict__ ei,
    int* __restrict__ gcu, int* __restrict__ gci,
    uint2* __restrict__ ebu, uint2* __restrict__ ebi,
    int E, int shu, int shi, int nbu, int nbi)
{
    __shared__ int hu[160], hi[160];
    int t = threadIdx.x;
    int base = blockIdx.x * 4096;
    if (t < 160) { hu[t] = 0; hi[t] = 0; }
    __syncthreads();
    int n = min(4096, E - base);
    int us[16], is_[16];
#pragma unroll 4
    for (int k = 0; k < 16; ++k) {
        int idx = k * 256 + t;
        if (idx < n) {
            us[k] = eu[base + idx];
            is_[k] = ei[base + idx];
            atomicAdd(&hu[us[k] >> shu], 1);
            atomicAdd(&hi[is_[k] >> shi], 1);
        } else us[k] = -1;
    }
    __syncthreads();
    if (t < nbu) { int c = hu[t]; hu[t] = c ? atomicAdd(&gcu[t], c) : 0; }
    if (t < nbi) { int c = hi[t]; hi[t] = c ? atomicAdd(&gci[t], c) : 0; }
    __syncthreads();
#pragma unroll 4
    for (int k = 0; k < 16; ++k) {
        if (us[k] >= 0) {
            int p1 = atomicAdd(&hu[us[k] >> shu], 1);
            ebu[p1] = make_uint2((unsigned)us[k], (unsigned)is_[k]);
            int p2 = atomicAdd(&hi[is_[k] >> shi], 1);
            ebi[p2] = make_uint2((unsigned)is_[k], (unsigned)us[k]);
        }
    }
}

// ---------------- CSR build: per-bucket offsets + adjacency (u and i sides) ----------------
__global__ __launch_bounds__(256) void fill2_all(
    const uint2* __restrict__ ebu, const int* __restrict__ bbu,
    int* __restrict__ off_u, int* __restrict__ end_u, int* __restrict__ adj_u,
    int NBU, int U,
    const uint2* __restrict__ ebi, const int* __restrict__ bbi,
    int* __restrict__ off_i, int* __restrict__ end_i, int* __restrict__ adj_i, int I)
{
    __shared__ int lcnt[512];
    __shared__ int lcur[512];
    bool isU = (int)blockIdx.x < NBU;
    const uint2* ebuf = isU ? ebu : ebi;
    const int* bbase  = isU ? bbu : bbi;
    int* off  = isU ? off_u : off_i;
    int* end_ = isU ? end_u : end_i;
    int* adj  = isU ? adj_u : adj_i;
    int span_sh = isU ? 9 : 8;
    int nrows = isU ? U : I;
    int b = isU ? blockIdx.x : blockIdx.x - NBU;

    int t = threadIdx.x;
    int rbase = b << span_sh;
    int span = min(1 << span_sh, nrows - rbase);
    int regbeg = bbase[b], regend = bbase[b + 1];
    for (int j = t; j < span; j += 256) lcnt[j] = 0;
    __syncthreads();
    for (int e = regbeg + t; e < regend; e += 256)
        atomicAdd(&lcnt[ebuf[e].x - rbase], 1);
    __syncthreads();
    int c0 = (2 * t < span) ? lcnt[2 * t] : 0;
    int c1 = (2 * t + 1 < span) ? lcnt[2 * t + 1] : 0;
    int ex = blk_excl_scan(c0 + c1, t);
    if (2 * t < span) {
        int beg = regbeg + ex;
        off[rbase + 2 * t] = beg;
        end_[rbase + 2 * t] = beg + c0;
        lcur[2 * t] = beg;
    }
    if (2 * t + 1 < span) {
        int beg = regbeg + ex + c0;
        off[rbase + 2 * t + 1] = beg;
        end_[rbase + 2 * t + 1] = beg + c1;
        lcur[2 * t + 1] = beg;
    }
    __syncthreads();
    for (int e = regbeg + t; e < regend; e += 256) {
        uint2 p = ebuf[e];
        int slot = atomicAdd(&lcur[p.x - rbase], 1);
        adj[slot] = (int)p.y;
    }
}

// ---------------- gather u+i in one launch ----------------
__global__ __launch_bounds__(256) void gather_all(
    const short* __restrict__ embU, const short* __restrict__ embI,
    const int* __restrict__ off_u, const int* __restrict__ end_u, const int* __restrict__ adj_u,
    const int* __restrict__ off_i, const int* __restrict__ end_i, const int* __restrict__ adj_i,
    short* __restrict__ nub, short* __restrict__ nib, int U, int I)
{
    int gw = (blockIdx.x * 256 + threadIdx.x) >> 6;
    int lane = threadIdx.x & 63;
    const short* emb; const int *offp, *endp, *adjp; short* outp; int row;
    if (gw < U)          { emb = embU; offp = off_u; endp = end_u; adjp = adj_u; outp = nub; row = gw; }
    else if (gw < U + I) { emb = embI; offp = off_i; endp = end_i; adjp = adj_i; outp = nib; row = gw - U; }
    else return;

    int beg = offp[row], end = endp[row];
    float ax = 0.f, ay = 0.f;
    int j = beg;
    for (; j + 3 < end; j += 4) {
        unsigned a = *(const unsigned*)(emb + (size_t)adjp[j]     * D_ + lane * 2);
        unsigned b = *(const unsigned*)(emb + (size_t)adjp[j + 1] * D_ + lane * 2);
        unsigned c = *(const unsigned*)(emb + (size_t)adjp[j + 2] * D_ + lane * 2);
        unsigned d = *(const unsigned*)(emb + (size_t)adjp[j + 3] * D_ + lane * 2);
        ax += b2f((short)(a & 0xffff)) + b2f((short)(b & 0xffff))
            + b2f((short)(c & 0xffff)) + b2f((short)(d & 0xffff));
        ay += b2f((short)(a >> 16)) + b2f((short)(b >> 16))
            + b2f((short)(c >> 16)) + b2f((short)(d >> 16));
    }
    for (; j < end; ++j) {
        unsigned a = *(const unsigned*)(emb + (size_t)adjp[j] * D_ + lane * 2);
        ax += b2f((short)(a & 0xffff));
        ay += b2f((short)(a >> 16));
    }
    unsigned o = ((unsigned)(unsigned short)f2b(ay) << 16) | (unsigned short)(unsigned)f2b(ax);
    *(unsigned*)(outp + (size_t)row * D_ + lane * 2) = o;
}

// ---------------- fused gemm + MLP + norm; y->bf16; per-block colsum partial ----------------
struct MlpArgs {
    const short *uA0, *uA1, *uA2, *uA3;
    const short *iA0, *iA1;
    const short *uWg, *uW1, *uW2, *uW3;
    const short *iWg, *iW1, *iW2, *iW3;
    const float *ubg, *ub1, *ub2, *ub3;
    const float *ibg, *ib1, *ib2, *ib3;
    short *uY, *iY;
    float *uPart, *iPart;
    int UB;
};

__global__ __launch_bounds__(256, 3) void fused_mlp_all(MlpArgs P)
{
    __shared__ char pool[47104];
    __shared__ float wred[4][16];
    __shared__ float nrms[16];

    short* x2 = (short*)pool;
    short* xc = (short*)(pool + 4096);
    short* h1 = (short*)(pool + 4096);
    short* h2 = (short*)(pool + 45056);
    short* yb = (short*)pool;

    const int t = threadIdx.x;
    const int l = t & 63;
    const int w = t >> 6;
    const int lr = l & 15;
    const int lg = l >> 4;

    const bool isU = (int)blockIdx.x < P.UB;
    const int bid = isU ? (int)blockIdx.x : (int)blockIdx.x - P.UB;
    const size_t rb0 = (size_t)bid * 16;
    const int CHSH = isU ? 6 : 5;           // log2(KCAT/8)
    const int KKG  = isU ? 16 : 8;          // KCAT/32
    const short* Wg = isU ? P.uWg : P.iWg;
    const short* W1 = isU ? P.uW1 : P.iW1;
    const short* W2 = isU ? P.uW2 : P.iW2;
    const short* W3 = isU ? P.uW3 : P.iW3;
    const float* bg = isU ? P.ubg : P.ibg;
    const float* b1 = isU ? P.ub1 : P.ib1;
    const float* b2 = isU ? P.ub2 : P.ib2;
    const float* b3 = isU ? P.ub3 : P.ib3;
    short* Ybf = isU ? P.uY : P.iY;
    float* part = (isU ? P.uPart : P.iPart) + (size_t)bid * DK_;

    // ---- stage concat-x into LDS (swizzled 16B slots) ----
    const int CH_ROW = 1 << CHSH;
    for (int idx = t; idx < (16 << CHSH); idx += 256) {
        int row = idx >> CHSH;
        int slot = idx & (CH_ROW - 1);
        int a = slot >> 4, cs = slot & 15;
        const short* src = isU ? (a == 0 ? P.uA0 : a == 1 ? P.uA1 : a == 2 ? P.uA2 : P.uA3)
                               : (a == 0 ? P.iA0 : P.iA1);
        bh8 v = *(const bh8*)(src + (rb0 + row) * D_ + cs * 8);
        int sl2 = slot ^ (row & 7);
        *(bh8*)(xc + (row << (CHSH + 3)) + sl2 * 8) = v;
    }
    __syncthreads();

    // ---- gemm: tmp = xcat @ Wg + bg -> x2 (bf16) ----
    {
        f32x4 accA0 = {0,0,0,0}, accB0 = accA0, accA1 = accA0, accB1 = accA0;
#pragma unroll 4
        for (int kk = 0; kk < KKG; ++kk) {
            int slot = kk * 4 + lg;
            bh8 af = *(const bh8*)(xc + (lr << (CHSH + 3)) + ((slot ^ (lr & 7)) * 8));
            bh8 b0 = *(const bh8*)(Wg + (((size_t)(2 * w) * KKG + kk) * 64 + l) * 8);
            bh8 b1v = *(const bh8*)(Wg + (((size_t)(2 * w + 1) * KKG + kk) * 64 + l) * 8);
            if (kk & 1) { accB0 = mfma16(af, b0, accB0); accB1 = mfma16(af, b1v, accB1); }
            else        { accA0 = mfma16(af, b0, accA0); accA1 = mfma16(af, b1v, accA1); }
        }
#pragma unroll
        for (int r = 0; r < 4; ++r) {
            int row = lg * 4 + r;
            int c0 = (2 * w) * 16 + lr;
            int c1 = c0 + 16;
            x2[row * 128 + (((c0 >> 3) ^ (row & 7)) * 8) + (l & 7)] = f2b(accA0[r] + accB0[r] + bg[c0]);
            x2[row * 128 + (((c1 >> 3) ^ (row & 7)) * 8) + (l & 7)] = f2b(accA1[r] + accB1[r] + bg[c1]);
        }
    }
    __syncthreads();

    // ---- phase 1: h1 = tanh(x2 @ W1 + b1) ----
    {
        bh8 a1f[4];
#pragma unroll
        for (int kk = 0; kk < 4; ++kk) {
            int slot = kk * 4 + lg;
            a1f[kk] = *(const bh8*)(x2 + lr * 128 + (slot ^ (lr & 7)) * 8);
        }
#pragma unroll 2
        for (int tile = w * 20; tile < w * 20 + 20; ++tile) {
            float bv = b1[tile * 16 + lr];
            f32x4 acc = {bv, bv, bv, bv};
#pragma unroll
            for (int kk = 0; kk < 4; ++kk) {
                bh8 bf_ = *(const bh8*)(W1 + (((size_t)tile * 4 + kk) * 64 + l) * 8);
                acc = mfma16(a1f[kk], bf_, acc);
            }
#pragma unroll
            for (int r = 0; r < 4; ++r) {
                int row = lg * 4 + r;
                int col = tile * 16 + lr;
                h1[row * 1280 + (((col >> 3) ^ (row & 7)) * 8) + (l & 7)] = f2b(tanh_fast(acc[r]));
            }
        }
    }
    __syncthreads();

    // ---- phase 2: h2 = tanh(h1 @ W2 + b2) ----
    {
        float bv = b2[w * 16 + lr];
        f32x4 accA = {bv, bv, bv, bv}, accB = {0,0,0,0};
#pragma unroll 4
        for (int kk = 0; kk < 40; ++kk) {
            int slot = kk * 4 + lg;
            bh8 af = *(const bh8*)(h1 + lr * 1280 + (slot ^ (lr & 7)) * 8);
            bh8 bf_ = *(const bh8*)(W2 + (((size_t)w * 40 + kk) * 64 + l) * 8);
            if (kk & 1) accB = mfma16(af, bf_, accB);
            else        accA = mfma16(af, bf_, accA);
        }
#pragma unroll
        for (int r = 0; r < 4; ++r) {
            int row = lg * 4 + r;
            int col = w * 16 + lr;
            h2[row * 64 + (((col >> 3) ^ (row & 7)) * 8) + (l & 7)] = f2b(tanh_fast(accA[r] + accB[r]));
        }
    }
    __syncthreads();

    // ---- phase 3: y = h2 @ W3 + b3 -> ybuf(bf16), ssq ----
    {
        bh8 a3[2];
#pragma unroll
        for (int kk = 0; kk < 2; ++kk) {
            int slot = kk * 4 + lg;
            a3[kk] = *(const bh8*)(h2 + lr * 64 + (slot ^ (lr & 7)) * 8);
        }
        float ssq[4] = {0.f, 0.f, 0.f, 0.f};
#pragma unroll 2
        for (int tile = w * 20; tile < w * 20 + 20; ++tile) {
            float bv = b3[tile * 16 + lr];
            f32x4 acc = {bv, bv, bv, bv};
            bh8 b0 = *(const bh8*)(W3 + (((size_t)tile * 2 + 0) * 64 + l) * 8);
            bh8 b1v = *(const bh8*)(W3 + (((size_t)tile * 2 + 1) * 64 + l) * 8);
            acc = mfma16(a3[0], b0, acc);
            acc = mfma16(a3[1], b1v, acc);
            bh4 pk;
#pragma unroll
            for (int r = 0; r < 4; ++r) {
                ssq[r] = fmaf(acc[r], acc[r], ssq[r]);
                pk[r] = f2b(acc[r]);
            }
            *(bh4*)(yb + tile * 260 + l * 4) = pk;
        }
#pragma unroll
        for (int off = 1; off < 16; off <<= 1) {
#pragma unroll
            for (int r = 0; r < 4; ++r) ssq[r] += __shfl_xor(ssq[r], off);
        }
        if (lr == 0) {
#pragma unroll
            for (int r = 0; r < 4; ++r) wred[w][lg * 4 + r] = ssq[r];
        }
    }
    __syncthreads();
    if (t < 16) {
        float s = wred[0][t] + wred[1][t] + wred[2][t] + wred[3][t];
        nrms[t] = 1.f / fmaxf(sqrtf(s), 1e-12f);
    }
    __syncthreads();

    // ---- writeout: normalized bf16; per-block colsum partial (non-atomic) ----
    {
        float csum[5] = {0.f, 0.f, 0.f, 0.f, 0.f};
        for (int row = 0; row < 16; ++row) {
            float nv = nrms[row];
            int lph = (row >> 2) << 4;
            int r = row & 3;
#pragma unroll
            for (int ch = 0; ch < 5; ++ch) {
                int c = ch * 256 + t;
                int tile = c >> 4;
                int lanep = lph | (c & 15);
                float v = b2f(yb[tile * 260 + lanep * 4 + r]) * nv;
                Ybf[(rb0 + row) * DK_ + c] = f2b(v);
                csum[ch] += v;
            }
        }
#pragma unroll
        for (int ch = 0; ch < 5; ++ch) part[ch * 256 + t] = csum[ch];
    }
}

// ---------------- reduce per-block colsum partials -> bsu/bsi ----------------
__global__ __launch_bounds__(256) void finalize_bias(
    const float* __restrict__ partU, const float* __restrict__ partI,
    float* __restrict__ bsu, float* __restrict__ bsi, int NU, int NI)
{
    int c = blockIdx.x * 256 + threadIdx.x;     // grid.x = 5 -> c < 1280
    int z = blockIdx.z;
    const float* part = z ? partI : partU;
    float* dst = z ? bsi : bsu;
    int M = z ? NI : NU;
    int chunk = (M + gridDim.y - 1) / gridDim.y;
    int r0 = blockIdx.y * chunk;
    int r1 = min(M, r0 + chunk);
    if (r0 >= r1) return;
    float s = 0.f;
    for (int r = r0; r < r1; ++r) s += part[(size_t)r * DK_ + c];
    atomicAdd(&dst[c], s);
}

// ---------------- softmax u (over D, stride K) + i (over K, stride D), one launch ----------------
__global__ __launch_bounds__(64) void softmax_all(
    const short* __restrict__ Yu, const short* __restrict__ Yi,
    const float* __restrict__ bsu, const float* __restrict__ bsi,
    float invU, float invI,
    float* __restrict__ outu, float* __restrict__ outi, int U, int I)
{
    __shared__ float rowb[DK_];
    int b = blockIdx.x;
    int t = threadIdx.x;
    if (b < U) {
        size_t base = (size_t)b * DK_;
        for (int i = t; i < DK_ / 4; i += 64) {
            uint2 a = ((const uint2*)(Yu + base))[i];
            float4 bv = ((const float4*)bsu)[i];
            rowb[4 * i + 0] = b2f((short)(a.x & 0xffff)) + bv.x * invU;
            rowb[4 * i + 1] = b2f((short)(a.x >> 16))    + bv.y * invU;
            rowb[4 * i + 2] = b2f((short)(a.y & 0xffff)) + bv.z * invU;
            rowb[4 * i + 3] = b2f((short)(a.y >> 16))    + bv.w * invU;
        }
        __syncthreads();
#pragma unroll 1
        for (int k = 0; k < K_; ++k) {
            float v0 = rowb[t * K_ + k];
            float v1 = rowb[(t + 64) * K_ + k];
            float m = fmaxf(v0, v1);
            for (int off = 32; off; off >>= 1) m = fmaxf(m, __shfl_xor(m, off));
            float e0 = expf(v0 - m), e1 = expf(v1 - m);
            float s = e0 + e1;
            for (int off = 32; off; off >>= 1) s += __shfl_xor(s, off);
            float rs = 1.f / s;
            rowb[t * K_ + k] = e0 * rs;
            rowb[(t + 64) * K_ + k] = e1 * rs;
        }
        __syncthreads();
        for (int i = t; i < DK_ / 4; i += 64)
            ((float4*)(outu + base))[i] = ((const float4*)rowb)[i];
    } else {
        int it = b - U;
        if (it >= I) return;
        size_t base = (size_t)it * DK_;
        float v0[K_], v1[K_];
        float m0 = -1e30f, m1 = -1e30f;
#pragma unroll
        for (int k = 0; k < K_; ++k) {
            unsigned a = *(const unsigned*)(Yi + base + k * D_ + 2 * t);
            float2 bv = ((const float2*)(bsi + k * D_))[t];
            v0[k] = b2f((short)(a & 0xffff)) + bv.x * invI;
            v1[k] = b2f((short)(a >> 16))    + bv.y * invI;
            m0 = fmaxf(m0, v0[k]); m1 = fmaxf(m1, v1[k]);
        }
        float s0 = 0.f, s1 = 0.f;
#pragma unroll
        for (int k = 0; k < K_; ++k) {
            v0[k] = expf(v0[k] - m0); s0 += v0[k];
            v1[k] = expf(v1[k] - m1); s1 += v1[k];
        }
        float r0 = 1.f / s0, r1 = 1.f / s1;
#pragma unroll
        for (int k = 0; k < K_; ++k) {
            float2 o; o.x = v0[k] * r0; o.y = v1[k] * r1;
            ((float2*)(outi + base + k * D_))[t] = o;
        }
    }
}

extern "C" void kernel_launch(void* const* d_in, const int* in_sizes, int n_in,
                              void* d_out, int out_size, void* d_ws, size_t ws_size,
                              hipStream_t stream)
{
    const float* uemb_s   = (const float*)d_in[0];
    const float* iemb_s   = (const float*)d_in[1];
    const float* uemb_t   = (const float*)d_in[2];
    const float* u_emb_sp = (const float*)d_in[3];
    const int*   eu       = (const int*)d_in[4];
    const int*   ei       = (const int*)d_in[5];
    const float* Wu  = (const float*)d_in[6];
    const float* bu  = (const float*)d_in[7];
    const float* Wi  = (const float*)d_in[8];
    const float* bi  = (const float*)d_in[9];
    const float* m1w1 = (const float*)d_in[10];
    const float* m1b1 = (const float*)d_in[11];
    const float* m1w2 = (const float*)d_in[12];
    const float* m1b2 = (const float*)d_in[13];
    const float* m1w3 = (const float*)d_in[14];
    const float* m1b3 = (const float*)d_in[15];
    const float* m2w1 = (const float*)d_in[16];
    const float* m2b1 = (const float*)d_in[17];
    const float* m2w2 = (const float*)d_in[18];
    const float* m2b2 = (const float*)d_in[19];
    const float* m2w3 = (const float*)d_in[20];
    const float* m2b3 = (const float*)d_in[21];

    const int U = in_sizes[0] / D_;
    const int I = in_sizes[1] / D_;
    const int E = in_sizes[4];

    const int SHU = 9, SHI = 8;
    const int NBU = (U + 511) >> 9;
    const int NBI = (I + 255) >> 8;
    const int UB = U / 16, IB = I / 16;

    char* p = (char*)d_ws;
    auto alloc = [&](size_t bytes) { char* r = p; p += (bytes + 255) & ~(size_t)255; return r; };

    short* usb  = (short*)alloc((size_t)U * D_ * 2);
    short* utb  = (short*)alloc((size_t)U * D_ * 2);
    short* uspb = (short*)alloc((size_t)U * D_ * 2);
    short* uavg = (short*)alloc((size_t)U * D_ * 2);
    short* isb  = (short*)alloc((size_t)I * D_ * 2);
    short* nub  = (short*)alloc((size_t)U * D_ * 2);
    short* nib  = (short*)alloc((size_t)I * D_ * 2);
    short* ybu  = (short*)alloc((size_t)U * DK_ * 2);
    short* ybi  = (short*)alloc((size_t)I * DK_ * 2);
    float* partU = (float*)alloc((size_t)UB * DK_ * 4);
    float* partI = (float*)alloc((size_t)IB * DK_ * 4);
    short* WgU  = (short*)alloc(512 * 128 * 2);
    short* WgI  = (short*)alloc(256 * 128 * 2);
    short* W1U  = (short*)alloc(128 * 1280 * 2);
    short* W2U  = (short*)alloc(1280 * 64 * 2);
    short* W3U  = (short*)alloc(64 * 1280 * 2);
    short* W1I  = (short*)alloc(128 * 1280 * 2);
    short* W2I  = (short*)alloc(1280 * 64 * 2);
    short* W3I  = (short*)alloc(64 * 1280 * 2);
    int*   zbuf = (int*)alloc((320 + 2 * DK_) * 4);    // bcnt | bsu | bsi, one memset
    int* bcnt_u = zbuf;
    int* bcnt_i = zbuf + 160;
    float* bsu  = (float*)(zbuf + 320);
    float* bsi  = bsu + DK_;
    int* gcur_u = (int*)alloc(160 * 4);
    int* gcur_i = (int*)alloc(160 * 4);
    int* bbase_u = (int*)alloc(161 * 4);
    int* bbase_i = (int*)alloc(161 * 4);
    int* off_u  = (int*)alloc((size_t)U * 4);
    int* end_u  = (int*)alloc((size_t)U * 4);
    int* off_i  = (int*)alloc((size_t)I * 4);
    int* end_i  = (int*)alloc((size_t)I * 4);
    uint2* ebu  = (uint2*)alloc((size_t)E * 8);
    uint2* ebi  = (uint2*)alloc((size_t)E * 8);
    int* adj_u  = (int*)alloc((size_t)E * 4);
    int* adj_i  = (int*)alloc((size_t)E * 4);

    float* outu = (float*)d_out;
    float* outi = outu + (size_t)U * DK_;

    hipMemsetAsync(zbuf, 0, (320 + 2 * DK_) * 4, stream);

    int n4u = U * D_ / 4, n4i = I * D_ / 4;
    cvt_all<<<(n4u + n4i + 255) / 256, 256, 0, stream>>>(
        uemb_s, uemb_t, u_emb_sp, iemb_s, usb, utb, uspb, uavg, isb, n4u, n4i);

    PackArgs pa;
    pa.W[0] = Wu;   pa.o[0] = WgU; pa.K[0] = 512;  pa.N[0] = 128;
    pa.W[1] = Wi;   pa.o[1] = WgI; pa.K[1] = 256;  pa.N[1] = 128;
    pa.W[2] = m1w1; pa.o[2] = W1U; pa.K[2] = 128;  pa.N[2] = 1280;
    pa.W[3] = m1w2; pa.o[3] = W2U; pa.K[3] = 1280; pa.N[3] = 64;
    pa.W[4] = m1w3; pa.o[4] = W3U; pa.K[4] = 64;   pa.N[4] = 1280;
    pa.W[5] = m2w1; pa.o[5] = W1I; pa.K[5] = 128;  pa.N[5] = 1280;
    pa.W[6] = m2w2; pa.o[6] = W2I; pa.K[6] = 1280; pa.N[6] = 64;
    pa.W[7] = m2w3; pa.o[7] = W3I; pa.K[7] = 64;   pa.N[7] = 1280;
    pack_all<<<dim3(640, 8), 256, 0, stream>>>(pa);

    int pb = (E + 4095) / 4096;
    bhist_kernel<<<pb, 256, 0, stream>>>(eu, ei, bcnt_u, bcnt_i, E, SHU, SHI, NBU, NBI);
    binit_kernel<<<1, 256, 0, stream>>>(bcnt_u, gcur_u, bbase_u, NBU,
                                        bcnt_i, gcur_i, bbase_i, NBI, E);
    partition_kernel<<<pb, 256, 0, stream>>>(eu, ei, gcur_u, gcur_i, ebu, ebi,
                                             E, SHU, SHI, NBU, NBI);
    fill2_all<<<NBU + NBI, 256, 0, stream>>>(ebu, bbase_u, off_u, end_u, adj_u, NBU, U,
                                             ebi, bbase_i, off_i, end_i, adj_i, I);

    gather_all<<<(U + I + 3) / 4, 256, 0, stream>>>(
        isb, uavg, off_u, end_u, adj_u, off_i, end_i, adj_i, nub, nib, U, I);

    MlpArgs ma;
    ma.uA0 = usb; ma.uA1 = utb; ma.uA2 = uspb; ma.uA3 = nub;
    ma.iA0 = isb; ma.iA1 = nib;
    ma.uWg = WgU; ma.uW1 = W1U; ma.uW2 = W2U; ma.uW3 = W3U;
    ma.iWg = WgI; ma.iW1 = W1I; ma.iW2 = W2I; ma.iW3 = W3I;
    ma.ubg = bu; ma.ub1 = m1b1; ma.ub2 = m1b2; ma.ub3 = m1b3;
    ma.ibg = bi; ma.ib1 = m2b1; ma.ib2 = m2b2; ma.ib3 = m2b3;
    ma.uY = ybu; ma.iY = ybi;
    ma.uPart = partU; ma.iPart = partI;
    ma.UB = UB;
    fused_mlp_all<<<UB + IB, 256, 0, stream>>>(ma);

    finalize_bias<<<dim3(5, 40, 2), 256, 0, stream>>>(partU, partI, bsu, bsi, UB, IB);

    softmax_all<<<U + I, 64, 0, stream>>>(ybu, ybi, bsu, bsi,
                                          1.0f / (float)U, 1.0f / (float)I, outu, outi, U, I);
}